// Round 2
// baseline (1313.019 us; speedup 1.0000x reference)
//
#include <hip/hip_runtime.h>

#define NN 50000
#define NE 800000
#define HID 128
#define NG 128
#define NOUT 10
#define FEAT 512   // 128*3 + 128
#define BN_EPS 1e-5f

__device__ __forceinline__ void fma4(float4& acc, float s, const float4& v) {
    acc.x = fmaf(s, v.x, acc.x);
    acc.y = fmaf(s, v.y, acc.y);
    acc.z = fmaf(s, v.z, acc.z);
    acc.w = fmaf(s, v.w, acc.w);
}

__device__ __forceinline__ int lbound(const int* __restrict__ b, int n, int v) {
    int lo = 0, hi = n;
    while (lo < hi) { int mid = (lo + hi) >> 1; if (b[mid] < v) lo = mid + 1; else hi = mid; }
    return lo;
}

// ---- degree ----
__global__ void k_deg_init(float* __restrict__ deg) {
    int i = blockIdx.x * 256 + threadIdx.x;
    if (i < NN) deg[i] = 1.0f;   // self-loop
}
__global__ void k_deg_edges(const int* __restrict__ ei, float* __restrict__ deg) {
    int e = blockIdx.x * 256 + threadIdx.x;
    if (e < NE) atomicAdd(&deg[ei[NE + e]], 1.0f);   // dst-indegree
}
__global__ void k_dinv(float* __restrict__ deg) {
    int i = blockIdx.x * 256 + threadIdx.x;
    if (i < NN) deg[i] = rsqrtf(deg[i]);
}

// ---- per-row GEMM: t' = (H[row,:] @ W) * dinv[row]  -> A (msg src) and B (accum init = self-loop) ----
__global__ __launch_bounds__(256) void k_gemm(const float* __restrict__ H,
        const float* __restrict__ Wg, const float* __restrict__ dinv,
        float* __restrict__ A, float* __restrict__ B)
{
    __shared__ __align__(16) float wl[HID * HID];   // 64 KB
    __shared__ __align__(16) float hl[16 * 132];    // 16 rows, padded stride 132
    const int tid = threadIdx.x;
    // stage W once per block
#pragma unroll
    for (int i = 0; i < 16; ++i) {
        int flat = (i * 256 + tid) * 4;
        *(float4*)&wl[flat] = *(const float4*)&Wg[flat];
    }
    const int cg = (tid & 31) * 4;   // 4 output cols
    const int r0 = tid >> 5;         // rows r0 and r0+8 of the 16-row tile

    for (int base = blockIdx.x * 16; base < NN; base += gridDim.x * 16) {
        __syncthreads();
        // stage 16 input rows
#pragma unroll
        for (int j = 0; j < 2; ++j) {
            int flat = (j * 256 + tid) * 4;
            int r = flat >> 7, k = flat & 127;
            int row = base + r;
            float4 v = make_float4(0.f, 0.f, 0.f, 0.f);
            if (row < NN) v = *(const float4*)&H[row * HID + k];
            *(float4*)&hl[r * 132 + k] = v;
        }
        __syncthreads();
        float4 a0 = make_float4(0.f,0.f,0.f,0.f);
        float4 a1 = make_float4(0.f,0.f,0.f,0.f);
#pragma unroll 8
        for (int k = 0; k < HID; k += 4) {
            float4 ha = *(const float4*)&hl[r0 * 132 + k];
            float4 hb = *(const float4*)&hl[(r0 + 8) * 132 + k];
            float4 w0 = *(const float4*)&wl[(k + 0) * HID + cg];
            float4 w1 = *(const float4*)&wl[(k + 1) * HID + cg];
            float4 w2 = *(const float4*)&wl[(k + 2) * HID + cg];
            float4 w3 = *(const float4*)&wl[(k + 3) * HID + cg];
            fma4(a0, ha.x, w0); fma4(a0, ha.y, w1); fma4(a0, ha.z, w2); fma4(a0, ha.w, w3);
            fma4(a1, hb.x, w0); fma4(a1, hb.y, w1); fma4(a1, hb.z, w2); fma4(a1, hb.w, w3);
        }
        int row0 = base + r0, row1 = base + r0 + 8;
        if (row0 < NN) {
            float s = dinv[row0];
            a0.x *= s; a0.y *= s; a0.z *= s; a0.w *= s;
            *(float4*)&A[row0 * HID + cg] = a0;
            *(float4*)&B[row0 * HID + cg] = a0;
        }
        if (row1 < NN) {
            float s = dinv[row1];
            a1.x *= s; a1.y *= s; a1.z *= s; a1.w *= s;
            *(float4*)&A[row1 * HID + cg] = a1;
            *(float4*)&B[row1 * HID + cg] = a1;
        }
    }
}

// ---- edge scatter: B[dst,:] += A[src,:] ----
__global__ __launch_bounds__(256) void k_scatter(const float* __restrict__ A,
        float* __restrict__ B, const int* __restrict__ ei)
{
    const int c = threadIdx.x & 127;
    const int e0 = blockIdx.x * 2 + (threadIdx.x >> 7);
    const int stride = gridDim.x * 2;
    for (int e = e0; e < NE; e += stride) {
        int s = ei[e];
        int d = ei[NE + e];
        atomicAdd(&B[d * HID + c], A[s * HID + c]);
    }
}

// ---- epilogue: B = relu(((B*dinv) + bias - rm) * gamma*rsqrt(rv+eps) + beta) ----
__global__ void k_bnrelu(float* __restrict__ B, const float* __restrict__ dinv,
        const float* __restrict__ bs, const float* __restrict__ gam,
        const float* __restrict__ bet, const float* __restrict__ rm,
        const float* __restrict__ rv)
{
    int idx = blockIdx.x * 256 + threadIdx.x;
    if (idx >= NN * HID) return;
    int v = idx >> 7, c = idx & 127;
    float s = gam[c] * rsqrtf(rv[c] + BN_EPS);
    float val = B[idx] * dinv[v];
    float o = (val + bs[c] - rm[c]) * s + bet[c];
    B[idx] = fmaxf(o, 0.f);
}

// ---- per-graph mean-pool partial sums (one 128-col slice) ----
__global__ void k_pool(const float* __restrict__ F, const int* __restrict__ batch,
        float* __restrict__ pooled /* pre-offset by col slice */)
{
    int g = blockIdx.x >> 3;
    int chunk = blockIdx.x & 7;
    int c = threadIdx.x;   // 128
    int start = lbound(batch, NN, g);
    int end = lbound(batch, NN, g + 1);
    float acc = 0.f;
    for (int n = start + chunk; n < end; n += 8) acc += F[n * HID + c];
    atomicAdd(&pooled[g * FEAT + c], acc);
}

// ---- classifier + log_softmax ----
__global__ void k_final(const float* __restrict__ pooled, const int* __restrict__ batch,
        const float* __restrict__ Wc, const float* __restrict__ bc, float* __restrict__ out)
{
    __shared__ float lg[NOUT];
    int g = blockIdx.x;
    int t = threadIdx.x;  // 64
    int start = lbound(batch, NN, g);
    int end = lbound(batch, NN, g + 1);
    float inv = 1.f / fmaxf((float)(end - start), 1.f);
    if (t < NOUT) {
        float acc = bc[t];
        for (int c = 0; c < FEAT; ++c)
            acc = fmaf(pooled[g * FEAT + c] * inv, Wc[c * NOUT + t], acc);
        lg[t] = acc;
    }
    __syncthreads();
    if (t == 0) {
        float m = -1e30f;
        for (int o = 0; o < NOUT; ++o) m = fmaxf(m, lg[o]);
        float ssum = 0.f;
        for (int o = 0; o < NOUT; ++o) ssum += expf(lg[o] - m);
        float lse = m + logf(ssum);
        for (int o = 0; o < NOUT; ++o) out[g * NOUT + o] = lg[o] - lse;
    }
}

extern "C" void kernel_launch(void* const* d_in, const int* in_sizes, int n_in,
                              void* d_out, int out_size, void* d_ws, size_t ws_size,
                              hipStream_t stream)
{
    const float* x      = (const float*)d_in[0];
    const int*   ei     = (const int*)d_in[1];
    const int*   batch  = (const int*)d_in[2];
    const float* Ws     = (const float*)d_in[3];
    const float* bs     = (const float*)d_in[4];
    const float* gammas = (const float*)d_in[5];
    const float* betas  = (const float*)d_in[6];
    const float* rms    = (const float*)d_in[7];
    const float* rvs    = (const float*)d_in[8];
    const float* Wc     = (const float*)d_in[9];
    const float* bc     = (const float*)d_in[10];
    float* out = (float*)d_out;

    float* A    = (float*)d_ws;              // NN*HID
    float* B    = A + (size_t)NN * HID;      // NN*HID
    float* dinv = B + (size_t)NN * HID;      // NN
    float* pooled = dinv + NN;               // NG*FEAT

    hipMemsetAsync(pooled, 0, NG * FEAT * sizeof(float), stream);

    k_deg_init<<<(NN + 255) / 256, 256, 0, stream>>>(dinv);
    k_deg_edges<<<(NE + 255) / 256, 256, 0, stream>>>(ei, dinv);
    k_dinv<<<(NN + 255) / 256, 256, 0, stream>>>(dinv);

    // pool raw x into slice 0
    k_pool<<<NG * 8, 128, 0, stream>>>(x, batch, pooled + 0);

    const float* H = x;
    for (int L = 0; L < 3; ++L) {
        k_gemm<<<512, 256, 0, stream>>>(H, Ws + (size_t)L * HID * HID, dinv, A, B);
        k_scatter<<<4096, 256, 0, stream>>>(A, B, ei);
        k_bnrelu<<<(NN * HID + 255) / 256, 256, 0, stream>>>(
            B, dinv, bs + L * HID, gammas + L * HID, betas + L * HID,
            rms + L * HID, rvs + L * HID);
        k_pool<<<NG * 8, 128, 0, stream>>>(B, batch, pooled + (L + 1) * HID);
        H = B;
    }

    k_final<<<NG, 64, 0, stream>>>(pooled, batch, Wc, bc, out);
}

// Round 3
// 646.826 us; speedup vs baseline: 2.0299x; 2.0299x over previous
//
#include <hip/hip_runtime.h>

#define NN 50000
#define NE 800000
#define HID 128
#define NG 128
#define NOUT 10
#define FEAT 512   // 128*3 + 128
#define BN_EPS 1e-5f
#define NB ((NN + 255) / 256)   // 196 scan blocks

__device__ __forceinline__ void fma4(float4& acc, float s, const float4& v) {
    acc.x = fmaf(s, v.x, acc.x);
    acc.y = fmaf(s, v.y, acc.y);
    acc.z = fmaf(s, v.z, acc.z);
    acc.w = fmaf(s, v.w, acc.w);
}

__device__ __forceinline__ int lbound(const int* __restrict__ b, int n, int v) {
    int lo = 0, hi = n;
    while (lo < hi) { int mid = (lo + hi) >> 1; if (b[mid] < v) lo = mid + 1; else hi = mid; }
    return lo;
}

// ---- CSR build: count in-degree ----
__global__ void k_count(const int* __restrict__ ei, int* __restrict__ cnt) {
    int e = blockIdx.x * 256 + threadIdx.x;
    if (e < NE) atomicAdd(&cnt[ei[NE + e]], 1);
}
__global__ void k_dinv(const int* __restrict__ cnt, float* __restrict__ dinv) {
    int i = blockIdx.x * 256 + threadIdx.x;
    if (i < NN) dinv[i] = rsqrtf((float)cnt[i] + 1.0f);   // +1 self-loop
}
// block sums for hierarchical scan
__global__ void k_bsum(const int* __restrict__ cnt, int* __restrict__ bsum) {
    __shared__ int sh[256];
    int i = blockIdx.x * 256 + threadIdx.x;
    sh[threadIdx.x] = (i < NN) ? cnt[i] : 0;
    __syncthreads();
    for (int off = 128; off > 0; off >>= 1) {
        if (threadIdx.x < off) sh[threadIdx.x] += sh[threadIdx.x + off];
        __syncthreads();
    }
    if (threadIdx.x == 0) bsum[blockIdx.x] = sh[0];
}
__global__ void k_bscan(const int* __restrict__ bsum, int* __restrict__ bsumsc,
                        int* __restrict__ rowptr) {
    if (threadIdx.x == 0) {
        int run = 0;
        for (int b = 0; b < NB; ++b) { bsumsc[b] = run; run += bsum[b]; }
        rowptr[NN] = NE;
    }
}
__global__ void k_scan(const int* __restrict__ cnt, const int* __restrict__ bsumsc,
                       int* __restrict__ rowptr, int* __restrict__ cursor) {
    __shared__ int sh[256];
    int t = threadIdx.x;
    int i = blockIdx.x * 256 + t;
    int v = (i < NN) ? cnt[i] : 0;
    sh[t] = v;
    __syncthreads();
    for (int off = 1; off < 256; off <<= 1) {
        int add = (t >= off) ? sh[t - off] : 0;
        __syncthreads();
        sh[t] += add;
        __syncthreads();
    }
    if (i < NN) {
        int excl = sh[t] - v + bsumsc[blockIdx.x];
        rowptr[i] = excl;
        cursor[i] = excl;
    }
}
__global__ void k_fill(const int* __restrict__ ei, int* __restrict__ cursor,
                       int* __restrict__ csr) {
    int e = blockIdx.x * 256 + threadIdx.x;
    if (e < NE) {
        int pos = atomicAdd(&cursor[ei[NE + e]], 1);
        csr[pos] = ei[e];   // src
    }
}

// ---- per-row GEMM: A[row,:] = (H[row,:] @ W) * dinv[row] ----
__global__ __launch_bounds__(256) void k_gemm(const float* __restrict__ H,
        const float* __restrict__ Wg, const float* __restrict__ dinv,
        float* __restrict__ A)
{
    __shared__ __align__(16) float wl[HID * HID];   // 64 KB
    __shared__ __align__(16) float hl[16 * 132];    // 16 rows, padded stride 132
    const int tid = threadIdx.x;
#pragma unroll
    for (int i = 0; i < 16; ++i) {
        int flat = (i * 256 + tid) * 4;
        *(float4*)&wl[flat] = *(const float4*)&Wg[flat];
    }
    const int cg = (tid & 31) * 4;
    const int r0 = tid >> 5;

    for (int base = blockIdx.x * 16; base < NN; base += gridDim.x * 16) {
        __syncthreads();
#pragma unroll
        for (int j = 0; j < 2; ++j) {
            int flat = (j * 256 + tid) * 4;
            int r = flat >> 7, k = flat & 127;
            int row = base + r;
            float4 v = make_float4(0.f, 0.f, 0.f, 0.f);
            if (row < NN) v = *(const float4*)&H[row * HID + k];
            *(float4*)&hl[r * 132 + k] = v;
        }
        __syncthreads();
        float4 a0 = make_float4(0.f,0.f,0.f,0.f);
        float4 a1 = make_float4(0.f,0.f,0.f,0.f);
#pragma unroll 8
        for (int k = 0; k < HID; k += 4) {
            float4 ha = *(const float4*)&hl[r0 * 132 + k];
            float4 hb = *(const float4*)&hl[(r0 + 8) * 132 + k];
            float4 w0 = *(const float4*)&wl[(k + 0) * HID + cg];
            float4 w1 = *(const float4*)&wl[(k + 1) * HID + cg];
            float4 w2 = *(const float4*)&wl[(k + 2) * HID + cg];
            float4 w3 = *(const float4*)&wl[(k + 3) * HID + cg];
            fma4(a0, ha.x, w0); fma4(a0, ha.y, w1); fma4(a0, ha.z, w2); fma4(a0, ha.w, w3);
            fma4(a1, hb.x, w0); fma4(a1, hb.y, w1); fma4(a1, hb.z, w2); fma4(a1, hb.w, w3);
        }
        int row0 = base + r0, row1 = base + r0 + 8;
        if (row0 < NN) {
            float s = dinv[row0];
            a0.x *= s; a0.y *= s; a0.z *= s; a0.w *= s;
            *(float4*)&A[row0 * HID + cg] = a0;
        }
        if (row1 < NN) {
            float s = dinv[row1];
            a1.x *= s; a1.y *= s; a1.z *= s; a1.w *= s;
            *(float4*)&A[row1 * HID + cg] = a1;
        }
    }
}

// ---- pull aggregation + fused BN+ReLU + fused pool atomic ----
// B[d] = relu( BN( dinv[d] * (A[d] + sum_{s in in(d)} A[s]) + bias ) )
__global__ __launch_bounds__(256) void k_agg(const float* __restrict__ A,
        const int* __restrict__ rowptr, const int* __restrict__ csr,
        const float* __restrict__ dinv, const float* __restrict__ bs,
        const float* __restrict__ gam, const float* __restrict__ bet,
        const float* __restrict__ rm, const float* __restrict__ rv,
        const int* __restrict__ batch, float* __restrict__ pooled,
        float* __restrict__ B)
{
    const int d = blockIdx.x * 2 + (threadIdx.x >> 7);
    const int c = threadIdx.x & 127;
    float acc = A[d * HID + c];          // self-loop term
    int e = rowptr[d], e1 = rowptr[d + 1];
    for (; e + 1 < e1; e += 2) {
        int s0 = csr[e], s1 = csr[e + 1];
        float v0 = A[s0 * HID + c];
        float v1 = A[s1 * HID + c];
        acc += v0;
        acc += v1;
    }
    if (e < e1) acc += A[csr[e] * HID + c];
    float scale = gam[c] * rsqrtf(rv[c] + BN_EPS);
    float o = (acc * dinv[d] + bs[c] - rm[c]) * scale + bet[c];
    o = fmaxf(o, 0.f);
    B[d * HID + c] = o;
    atomicAdd(&pooled[batch[d] * FEAT + c], o);
}

// ---- per-graph mean-pool partial sums for raw x (slice 0) ----
__global__ void k_pool(const float* __restrict__ F, const int* __restrict__ batch,
        float* __restrict__ pooled)
{
    int g = blockIdx.x >> 3;
    int chunk = blockIdx.x & 7;
    int c = threadIdx.x;   // 128
    int start = lbound(batch, NN, g);
    int end = lbound(batch, NN, g + 1);
    float acc = 0.f;
    for (int n = start + chunk; n < end; n += 8) acc += F[n * HID + c];
    atomicAdd(&pooled[g * FEAT + c], acc);
}

// ---- classifier + log_softmax ----
__global__ void k_final(const float* __restrict__ pooled, const int* __restrict__ batch,
        const float* __restrict__ Wc, const float* __restrict__ bc, float* __restrict__ out)
{
    __shared__ float lg[NOUT];
    int g = blockIdx.x;
    int t = threadIdx.x;  // 64
    int start = lbound(batch, NN, g);
    int end = lbound(batch, NN, g + 1);
    float inv = 1.f / fmaxf((float)(end - start), 1.f);
    if (t < NOUT) {
        float acc = bc[t];
        for (int c = 0; c < FEAT; ++c)
            acc = fmaf(pooled[g * FEAT + c] * inv, Wc[c * NOUT + t], acc);
        lg[t] = acc;
    }
    __syncthreads();
    if (t == 0) {
        float m = -1e30f;
        for (int o = 0; o < NOUT; ++o) m = fmaxf(m, lg[o]);
        float ssum = 0.f;
        for (int o = 0; o < NOUT; ++o) ssum += expf(lg[o] - m);
        float lse = m + logf(ssum);
        for (int o = 0; o < NOUT; ++o) out[g * NOUT + o] = lg[o] - lse;
    }
}

extern "C" void kernel_launch(void* const* d_in, const int* in_sizes, int n_in,
                              void* d_out, int out_size, void* d_ws, size_t ws_size,
                              hipStream_t stream)
{
    const float* x      = (const float*)d_in[0];
    const int*   ei     = (const int*)d_in[1];
    const int*   batch  = (const int*)d_in[2];
    const float* Ws     = (const float*)d_in[3];
    const float* bs     = (const float*)d_in[4];
    const float* gammas = (const float*)d_in[5];
    const float* betas  = (const float*)d_in[6];
    const float* rms    = (const float*)d_in[7];
    const float* rvs    = (const float*)d_in[8];
    const float* Wc     = (const float*)d_in[9];
    const float* bc     = (const float*)d_in[10];
    float* out = (float*)d_out;

    float* A      = (float*)d_ws;               // NN*HID
    float* B      = A + (size_t)NN * HID;       // NN*HID
    float* dinv   = B + (size_t)NN * HID;       // NN
    float* pooled = dinv + NN;                  // NG*FEAT
    int*   cnt    = (int*)(pooled + NG * FEAT); // NN
    int*   rowptr = cnt + NN;                   // NN+1
    int*   cursor = rowptr + NN + 1;            // NN
    int*   bsum   = cursor + NN;                // NB
    int*   bsumsc = bsum + NB;                  // NB
    int*   csr    = bsumsc + NB;                // NE

    hipMemsetAsync(cnt, 0, NN * sizeof(int), stream);
    hipMemsetAsync(pooled, 0, NG * FEAT * sizeof(float), stream);

    // CSR build (once; reused for all 3 layers)
    k_count<<<(NE + 255) / 256, 256, 0, stream>>>(ei, cnt);
    k_dinv<<<(NN + 255) / 256, 256, 0, stream>>>(cnt, dinv);
    k_bsum<<<NB, 256, 0, stream>>>(cnt, bsum);
    k_bscan<<<1, 64, 0, stream>>>(bsum, bsumsc, rowptr);
    k_scan<<<NB, 256, 0, stream>>>(cnt, bsumsc, rowptr, cursor);
    k_fill<<<(NE + 255) / 256, 256, 0, stream>>>(ei, cursor, csr);

    // pool raw x into slice 0
    k_pool<<<NG * 8, 128, 0, stream>>>(x, batch, pooled + 0);

    const float* H = x;
    for (int L = 0; L < 3; ++L) {
        k_gemm<<<512, 256, 0, stream>>>(H, Ws + (size_t)L * HID * HID, dinv, A);
        k_agg<<<NN / 2, 256, 0, stream>>>(A, rowptr, csr, dinv,
            bs + L * HID, gammas + L * HID, betas + L * HID,
            rms + L * HID, rvs + L * HID,
            batch, pooled + (L + 1) * HID, B);
        H = B;
    }

    k_final<<<NG, 64, 0, stream>>>(pooled, batch, Wc, bc, out);
}

// Round 4
// 486.808 us; speedup vs baseline: 2.6972x; 1.3287x over previous
//
#include <hip/hip_runtime.h>

#define NN 50000
#define NE 800000
#define HID 128
#define NG 128
#define NOUT 10
#define FEAT 512   // 128*3 + 128
#define BN_EPS 1e-5f
#define NB ((NN + 255) / 256)   // 196 scan blocks

__device__ __forceinline__ void fma4(float4& acc, float s, const float4& v) {
    acc.x = fmaf(s, v.x, acc.x);
    acc.y = fmaf(s, v.y, acc.y);
    acc.z = fmaf(s, v.z, acc.z);
    acc.w = fmaf(s, v.w, acc.w);
}

__device__ __forceinline__ int lbound(const int* __restrict__ b, int n, int v) {
    int lo = 0, hi = n;
    while (lo < hi) { int mid = (lo + hi) >> 1; if (b[mid] < v) lo = mid + 1; else hi = mid; }
    return lo;
}

// ---- CSR build: count in-degree ----
__global__ void k_count(const int* __restrict__ ei, int* __restrict__ cnt) {
    int e = blockIdx.x * 256 + threadIdx.x;
    if (e < NE) atomicAdd(&cnt[ei[NE + e]], 1);
}
__global__ void k_dinv(const int* __restrict__ cnt, float* __restrict__ dinv) {
    int i = blockIdx.x * 256 + threadIdx.x;
    if (i < NN) dinv[i] = rsqrtf((float)cnt[i] + 1.0f);   // +1 self-loop
}
__global__ void k_bsum(const int* __restrict__ cnt, int* __restrict__ bsum) {
    __shared__ int sh[256];
    int i = blockIdx.x * 256 + threadIdx.x;
    sh[threadIdx.x] = (i < NN) ? cnt[i] : 0;
    __syncthreads();
    for (int off = 128; off > 0; off >>= 1) {
        if (threadIdx.x < off) sh[threadIdx.x] += sh[threadIdx.x + off];
        __syncthreads();
    }
    if (threadIdx.x == 0) bsum[blockIdx.x] = sh[0];
}
__global__ void k_bscan(const int* __restrict__ bsum, int* __restrict__ bsumsc,
                        int* __restrict__ rowptr) {
    if (threadIdx.x == 0) {
        int run = 0;
        for (int b = 0; b < NB; ++b) { bsumsc[b] = run; run += bsum[b]; }
        rowptr[NN] = NE;
    }
}
__global__ void k_scan(const int* __restrict__ cnt, const int* __restrict__ bsumsc,
                       int* __restrict__ rowptr, int* __restrict__ cursor) {
    __shared__ int sh[256];
    int t = threadIdx.x;
    int i = blockIdx.x * 256 + t;
    int v = (i < NN) ? cnt[i] : 0;
    sh[t] = v;
    __syncthreads();
    for (int off = 1; off < 256; off <<= 1) {
        int add = (t >= off) ? sh[t - off] : 0;
        __syncthreads();
        sh[t] += add;
        __syncthreads();
    }
    if (i < NN) {
        int excl = sh[t] - v + bsumsc[blockIdx.x];
        rowptr[i] = excl;
        cursor[i] = excl;
    }
}
__global__ void k_fill(const int* __restrict__ ei, int* __restrict__ cursor,
                       int* __restrict__ csr) {
    int e = blockIdx.x * 256 + threadIdx.x;
    if (e < NE) {
        int pos = atomicAdd(&cursor[ei[NE + e]], 1);
        csr[pos] = ei[e];   // src
    }
}

// ---- per-row GEMM: A[row,:] = (H[row,:] @ W) * dinv[row] ----
__global__ __launch_bounds__(256) void k_gemm(const float* __restrict__ H,
        const float* __restrict__ Wg, const float* __restrict__ dinv,
        float* __restrict__ A)
{
    __shared__ __align__(16) float wl[HID * HID];   // 64 KB
    __shared__ __align__(16) float hl[16 * 132];
    const int tid = threadIdx.x;
#pragma unroll
    for (int i = 0; i < 16; ++i) {
        int flat = (i * 256 + tid) * 4;
        *(float4*)&wl[flat] = *(const float4*)&Wg[flat];
    }
    const int cg = (tid & 31) * 4;
    const int r0 = tid >> 5;

    for (int base = blockIdx.x * 16; base < NN; base += gridDim.x * 16) {
        __syncthreads();
#pragma unroll
        for (int j = 0; j < 2; ++j) {
            int flat = (j * 256 + tid) * 4;
            int r = flat >> 7, k = flat & 127;
            int row = base + r;
            float4 v = make_float4(0.f, 0.f, 0.f, 0.f);
            if (row < NN) v = *(const float4*)&H[row * HID + k];
            *(float4*)&hl[r * 132 + k] = v;
        }
        __syncthreads();
        float4 a0 = make_float4(0.f,0.f,0.f,0.f);
        float4 a1 = make_float4(0.f,0.f,0.f,0.f);
#pragma unroll 8
        for (int k = 0; k < HID; k += 4) {
            float4 ha = *(const float4*)&hl[r0 * 132 + k];
            float4 hb = *(const float4*)&hl[(r0 + 8) * 132 + k];
            float4 w0 = *(const float4*)&wl[(k + 0) * HID + cg];
            float4 w1 = *(const float4*)&wl[(k + 1) * HID + cg];
            float4 w2 = *(const float4*)&wl[(k + 2) * HID + cg];
            float4 w3 = *(const float4*)&wl[(k + 3) * HID + cg];
            fma4(a0, ha.x, w0); fma4(a0, ha.y, w1); fma4(a0, ha.z, w2); fma4(a0, ha.w, w3);
            fma4(a1, hb.x, w0); fma4(a1, hb.y, w1); fma4(a1, hb.z, w2); fma4(a1, hb.w, w3);
        }
        int row0 = base + r0, row1 = base + r0 + 8;
        if (row0 < NN) {
            float s = dinv[row0];
            a0.x *= s; a0.y *= s; a0.z *= s; a0.w *= s;
            *(float4*)&A[row0 * HID + cg] = a0;
        }
        if (row1 < NN) {
            float s = dinv[row1];
            a1.x *= s; a1.y *= s; a1.z *= s; a1.w *= s;
            *(float4*)&A[row1 * HID + cg] = a1;
        }
    }
}

// ---- pull aggregation + fused BN+ReLU + fused pool ----
// 1 node per wave, float2 per lane, 4-deep gather ILP.
__global__ __launch_bounds__(256) void k_agg(const float* __restrict__ A,
        const int* __restrict__ rowptr, const int* __restrict__ csr,
        const float* __restrict__ dinv, const float* __restrict__ bs,
        const float* __restrict__ gam, const float* __restrict__ bet,
        const float* __restrict__ rm, const float* __restrict__ rv,
        const int* __restrict__ batch, float* __restrict__ pooled,
        float* __restrict__ B)
{
    const int w = threadIdx.x >> 6;
    const int lane = threadIdx.x & 63;
    const int d = blockIdx.x * 4 + w;      // 12500 blocks cover NN exactly
    const float2* __restrict__ A2 = (const float2*)A;

    float2 acc = A2[d * 64 + lane];        // self-loop term
    int e = rowptr[d], e1 = rowptr[d + 1];
    for (; e + 3 < e1; e += 4) {
        int s0 = csr[e], s1 = csr[e + 1], s2 = csr[e + 2], s3 = csr[e + 3];
        float2 v0 = A2[s0 * 64 + lane];
        float2 v1 = A2[s1 * 64 + lane];
        float2 v2 = A2[s2 * 64 + lane];
        float2 v3 = A2[s3 * 64 + lane];
        acc.x += (v0.x + v1.x) + (v2.x + v3.x);
        acc.y += (v0.y + v1.y) + (v2.y + v3.y);
    }
    for (; e < e1; ++e) {
        float2 v = A2[csr[e] * 64 + lane];
        acc.x += v.x; acc.y += v.y;
    }

    const int c0 = lane * 2;
    float di = dinv[d];
    float sc0 = gam[c0] * rsqrtf(rv[c0] + BN_EPS);
    float sc1 = gam[c0 + 1] * rsqrtf(rv[c0 + 1] + BN_EPS);
    float o0 = fmaxf((acc.x * di + bs[c0] - rm[c0]) * sc0 + bet[c0], 0.f);
    float o1 = fmaxf((acc.y * di + bs[c0 + 1] - rm[c0 + 1]) * sc1 + bet[c0 + 1], 0.f);
    ((float2*)B)[d * 64 + lane] = make_float2(o0, o1);

    // block-level pool combine: batch sorted -> 4 nodes usually same graph
    __shared__ float2 po[4][64];
    __shared__ int bid[4];
    po[w][lane] = make_float2(o0, o1);
    if (lane == 0) bid[w] = batch[d];
    __syncthreads();
    if (w == 0) {
#pragma unroll
        for (int i = 0; i < 4; ++i) {
            bool lead = true;
            for (int j = 0; j < i; ++j) lead = lead && (bid[j] != bid[i]);
            if (lead) {
                float2 s = po[i][lane];
                for (int j = i + 1; j < 4; ++j)
                    if (bid[j] == bid[i]) { s.x += po[j][lane].x; s.y += po[j][lane].y; }
                atomicAdd(&pooled[bid[i] * FEAT + c0], s.x);
                atomicAdd(&pooled[bid[i] * FEAT + c0 + 1], s.y);
            }
        }
    }
}

// ---- per-graph mean-pool partial sums for raw x (slice 0) ----
__global__ void k_pool(const float* __restrict__ F, const int* __restrict__ batch,
        float* __restrict__ pooled)
{
    int g = blockIdx.x >> 3;
    int chunk = blockIdx.x & 7;
    int c = threadIdx.x;   // 128
    int start = lbound(batch, NN, g);
    int end = lbound(batch, NN, g + 1);
    float acc = 0.f;
    for (int n = start + chunk; n < end; n += 8) acc += F[n * HID + c];
    atomicAdd(&pooled[g * FEAT + c], acc);
}

// ---- classifier + log_softmax ----
__global__ void k_final(const float* __restrict__ pooled, const int* __restrict__ batch,
        const float* __restrict__ Wc, const float* __restrict__ bc, float* __restrict__ out)
{
    __shared__ float lg[NOUT];
    int g = blockIdx.x;
    int t = threadIdx.x;  // 64
    int start = lbound(batch, NN, g);
    int end = lbound(batch, NN, g + 1);
    float inv = 1.f / fmaxf((float)(end - start), 1.f);
    if (t < NOUT) {
        float acc = bc[t];
        for (int c = 0; c < FEAT; ++c)
            acc = fmaf(pooled[g * FEAT + c] * inv, Wc[c * NOUT + t], acc);
        lg[t] = acc;
    }
    __syncthreads();
    if (t == 0) {
        float m = -1e30f;
        for (int o = 0; o < NOUT; ++o) m = fmaxf(m, lg[o]);
        float ssum = 0.f;
        for (int o = 0; o < NOUT; ++o) ssum += expf(lg[o] - m);
        float lse = m + logf(ssum);
        for (int o = 0; o < NOUT; ++o) out[g * NOUT + o] = lg[o] - lse;
    }
}

extern "C" void kernel_launch(void* const* d_in, const int* in_sizes, int n_in,
                              void* d_out, int out_size, void* d_ws, size_t ws_size,
                              hipStream_t stream)
{
    const float* x      = (const float*)d_in[0];
    const int*   ei     = (const int*)d_in[1];
    const int*   batch  = (const int*)d_in[2];
    const float* Ws     = (const float*)d_in[3];
    const float* bs     = (const float*)d_in[4];
    const float* gammas = (const float*)d_in[5];
    const float* betas  = (const float*)d_in[6];
    const float* rms    = (const float*)d_in[7];
    const float* rvs    = (const float*)d_in[8];
    const float* Wc     = (const float*)d_in[9];
    const float* bc     = (const float*)d_in[10];
    float* out = (float*)d_out;

    float* A      = (float*)d_ws;               // NN*HID
    float* B      = A + (size_t)NN * HID;       // NN*HID
    float* dinv   = B + (size_t)NN * HID;       // NN
    float* pooled = dinv + NN;                  // NG*FEAT
    int*   cnt    = (int*)(pooled + NG * FEAT); // NN
    int*   rowptr = cnt + NN;                   // NN+1
    int*   cursor = rowptr + NN + 1;            // NN
    int*   bsum   = cursor + NN;                // NB
    int*   bsumsc = bsum + NB;                  // NB
    int*   csr    = bsumsc + NB;                // NE

    hipMemsetAsync(cnt, 0, NN * sizeof(int), stream);
    hipMemsetAsync(pooled, 0, NG * FEAT * sizeof(float), stream);

    // CSR build (once; reused for all 3 layers)
    k_count<<<(NE + 255) / 256, 256, 0, stream>>>(ei, cnt);
    k_dinv<<<(NN + 255) / 256, 256, 0, stream>>>(cnt, dinv);
    k_bsum<<<NB, 256, 0, stream>>>(cnt, bsum);
    k_bscan<<<1, 64, 0, stream>>>(bsum, bsumsc, rowptr);
    k_scan<<<NB, 256, 0, stream>>>(cnt, bsumsc, rowptr, cursor);
    k_fill<<<(NE + 255) / 256, 256, 0, stream>>>(ei, cursor, csr);

    // pool raw x into slice 0
    k_pool<<<NG * 8, 128, 0, stream>>>(x, batch, pooled + 0);

    const float* H = x;
    for (int L = 0; L < 3; ++L) {
        k_gemm<<<512, 256, 0, stream>>>(H, Ws + (size_t)L * HID * HID, dinv, A);
        k_agg<<<(NN + 3) / 4, 256, 0, stream>>>(A, rowptr, csr, dinv,
            bs + L * HID, gammas + L * HID, betas + L * HID,
            rms + L * HID, rvs + L * HID,
            batch, pooled + (L + 1) * HID, B);
        H = B;
    }

    k_final<<<NG, 64, 0, stream>>>(pooled, batch, Wc, bc, out);
}

// Round 5
// 473.282 us; speedup vs baseline: 2.7743x; 1.0286x over previous
//
#include <hip/hip_runtime.h>

#define NN 50000
#define NE 800000
#define HID 128
#define NG 128
#define NOUT 10
#define FEAT 512   // 128*3 + 128
#define BN_EPS 1e-5f
#define NB ((NN + 255) / 256)   // 196 scan blocks

__device__ __forceinline__ void fma4(float4& acc, float s, const float4& v) {
    acc.x = fmaf(s, v.x, acc.x);
    acc.y = fmaf(s, v.y, acc.y);
    acc.z = fmaf(s, v.z, acc.z);
    acc.w = fmaf(s, v.w, acc.w);
}
__device__ __forceinline__ void add4(float4& a, const float4& v) {
    a.x += v.x; a.y += v.y; a.z += v.z; a.w += v.w;
}

__device__ __forceinline__ int lbound(const int* __restrict__ b, int n, int v) {
    int lo = 0, hi = n;
    while (lo < hi) { int mid = (lo + hi) >> 1; if (b[mid] < v) lo = mid + 1; else hi = mid; }
    return lo;
}

// ---- CSR build: count in-degree ----
__global__ void k_count(const int* __restrict__ ei, int* __restrict__ cnt) {
    int e = blockIdx.x * 256 + threadIdx.x;
    if (e < NE) atomicAdd(&cnt[ei[NE + e]], 1);
}
__global__ void k_dinv(const int* __restrict__ cnt, float* __restrict__ dinv) {
    int i = blockIdx.x * 256 + threadIdx.x;
    if (i < NN) dinv[i] = rsqrtf((float)cnt[i] + 1.0f);   // +1 self-loop
}
__global__ void k_bsum(const int* __restrict__ cnt, int* __restrict__ bsum) {
    __shared__ int sh[256];
    int i = blockIdx.x * 256 + threadIdx.x;
    sh[threadIdx.x] = (i < NN) ? cnt[i] : 0;
    __syncthreads();
    for (int off = 128; off > 0; off >>= 1) {
        if (threadIdx.x < off) sh[threadIdx.x] += sh[threadIdx.x + off];
        __syncthreads();
    }
    if (threadIdx.x == 0) bsum[blockIdx.x] = sh[0];
}
__global__ void k_bscan(const int* __restrict__ bsum, int* __restrict__ bsumsc,
                        int* __restrict__ rowptr) {
    if (threadIdx.x == 0) {
        int run = 0;
        for (int b = 0; b < NB; ++b) { bsumsc[b] = run; run += bsum[b]; }
        rowptr[NN] = NE;
    }
}
__global__ void k_scan(const int* __restrict__ cnt, const int* __restrict__ bsumsc,
                       int* __restrict__ rowptr, int* __restrict__ cursor) {
    __shared__ int sh[256];
    int t = threadIdx.x;
    int i = blockIdx.x * 256 + t;
    int v = (i < NN) ? cnt[i] : 0;
    sh[t] = v;
    __syncthreads();
    for (int off = 1; off < 256; off <<= 1) {
        int add = (t >= off) ? sh[t - off] : 0;
        __syncthreads();
        sh[t] += add;
        __syncthreads();
    }
    if (i < NN) {
        int excl = sh[t] - v + bsumsc[blockIdx.x];
        rowptr[i] = excl;
        cursor[i] = excl;
    }
}
__global__ void k_fill(const int* __restrict__ ei, int* __restrict__ cursor,
                       int* __restrict__ csr) {
    int e = blockIdx.x * 256 + threadIdx.x;
    if (e < NE) {
        int pos = atomicAdd(&cursor[ei[NE + e]], 1);
        csr[pos] = ei[e];   // src
    }
}

// ---- per-row GEMM: A[row,:] = (H[row,:] @ W) * dinv[row] ----
__global__ __launch_bounds__(256) void k_gemm(const float* __restrict__ H,
        const float* __restrict__ Wg, const float* __restrict__ dinv,
        float* __restrict__ A)
{
    __shared__ __align__(16) float wl[HID * HID];   // 64 KB
    __shared__ __align__(16) float hl[16 * 132];
    const int tid = threadIdx.x;
#pragma unroll
    for (int i = 0; i < 16; ++i) {
        int flat = (i * 256 + tid) * 4;
        *(float4*)&wl[flat] = *(const float4*)&Wg[flat];
    }
    const int cg = (tid & 31) * 4;
    const int r0 = tid >> 5;

    for (int base = blockIdx.x * 16; base < NN; base += gridDim.x * 16) {
        __syncthreads();
#pragma unroll
        for (int j = 0; j < 2; ++j) {
            int flat = (j * 256 + tid) * 4;
            int r = flat >> 7, k = flat & 127;
            int row = base + r;
            float4 v = make_float4(0.f, 0.f, 0.f, 0.f);
            if (row < NN) v = *(const float4*)&H[row * HID + k];
            *(float4*)&hl[r * 132 + k] = v;
        }
        __syncthreads();
        float4 a0 = make_float4(0.f,0.f,0.f,0.f);
        float4 a1 = make_float4(0.f,0.f,0.f,0.f);
#pragma unroll 8
        for (int k = 0; k < HID; k += 4) {
            float4 ha = *(const float4*)&hl[r0 * 132 + k];
            float4 hb = *(const float4*)&hl[(r0 + 8) * 132 + k];
            float4 w0 = *(const float4*)&wl[(k + 0) * HID + cg];
            float4 w1 = *(const float4*)&wl[(k + 1) * HID + cg];
            float4 w2 = *(const float4*)&wl[(k + 2) * HID + cg];
            float4 w3 = *(const float4*)&wl[(k + 3) * HID + cg];
            fma4(a0, ha.x, w0); fma4(a0, ha.y, w1); fma4(a0, ha.z, w2); fma4(a0, ha.w, w3);
            fma4(a1, hb.x, w0); fma4(a1, hb.y, w1); fma4(a1, hb.z, w2); fma4(a1, hb.w, w3);
        }
        int row0 = base + r0, row1 = base + r0 + 8;
        if (row0 < NN) {
            float s = dinv[row0];
            a0.x *= s; a0.y *= s; a0.z *= s; a0.w *= s;
            *(float4*)&A[row0 * HID + cg] = a0;
        }
        if (row1 < NN) {
            float s = dinv[row1];
            a1.x *= s; a1.y *= s; a1.z *= s; a1.w *= s;
            *(float4*)&A[row1 * HID + cg] = a1;
        }
    }
}

// ---- pull aggregation + fused BN+ReLU + fused pool ----
// 2 nodes per wave (32 lanes each, float4/lane), 4-deep unroll -> 8 rows (4 KB) in flight.
__global__ __launch_bounds__(256) void k_agg(const float* __restrict__ A,
        const int* __restrict__ rowptr, const int* __restrict__ csr,
        const float* __restrict__ dinv, const float* __restrict__ bs,
        const float* __restrict__ gam, const float* __restrict__ bet,
        const float* __restrict__ rm, const float* __restrict__ rv,
        const int* __restrict__ batch, float* __restrict__ pooled,
        float* __restrict__ B)
{
    const int w = threadIdx.x >> 6;          // wave 0..3
    const int lane = threadIdx.x & 63;
    const int half = lane >> 5;              // node within wave
    const int l32 = lane & 31;
    const int nloc = w * 2 + half;           // node within block 0..7
    const int d = blockIdx.x * 8 + nloc;     // 6250 blocks cover NN exactly
    const float4* __restrict__ A4 = (const float4*)A;

    float4 acc = A4[d * 32 + l32];           // self-loop term
    int e = rowptr[d], e1 = rowptr[d + 1];
    for (; e + 3 < e1; e += 4) {
        int4 s4 = *(const int4*)&csr[e];     // 4 indices in one dwordx4
        float4 v0 = A4[s4.x * 32 + l32];
        float4 v1 = A4[s4.y * 32 + l32];
        float4 v2 = A4[s4.z * 32 + l32];
        float4 v3 = A4[s4.w * 32 + l32];
        add4(acc, v0); add4(acc, v1); add4(acc, v2); add4(acc, v3);
    }
    for (; e < e1; ++e) {
        float4 v = A4[csr[e] * 32 + l32];
        add4(acc, v);
    }

    const int c0 = l32 * 4;
    const float di = dinv[d];
    const float4 g4  = *(const float4*)&gam[c0];
    const float4 rv4 = *(const float4*)&rv[c0];
    const float4 b4  = *(const float4*)&bs[c0];
    const float4 rm4 = *(const float4*)&rm[c0];
    const float4 be4 = *(const float4*)&bet[c0];
    float4 o;
    o.x = fmaxf((acc.x * di + b4.x - rm4.x) * (g4.x * rsqrtf(rv4.x + BN_EPS)) + be4.x, 0.f);
    o.y = fmaxf((acc.y * di + b4.y - rm4.y) * (g4.y * rsqrtf(rv4.y + BN_EPS)) + be4.y, 0.f);
    o.z = fmaxf((acc.z * di + b4.z - rm4.z) * (g4.z * rsqrtf(rv4.z + BN_EPS)) + be4.z, 0.f);
    o.w = fmaxf((acc.w * di + b4.w - rm4.w) * (g4.w * rsqrtf(rv4.w + BN_EPS)) + be4.w, 0.f);
    ((float4*)B)[d * 32 + l32] = o;

    // block-level pool combine: batch sorted -> 8 nodes usually share a graph
    __shared__ float4 po[8][32];
    __shared__ int bid[8];
    po[nloc][l32] = o;
    if (lane == 0 || lane == 32) bid[nloc] = batch[d];
    __syncthreads();
    if (w == 0 && half == 0) {   // lanes 0..31
#pragma unroll
        for (int i = 0; i < 8; ++i) {
            bool lead = true;
            for (int j = 0; j < i; ++j) lead = lead && (bid[j] != bid[i]);
            if (lead) {
                float4 s = po[i][l32];
                for (int j = i + 1; j < 8; ++j)
                    if (bid[j] == bid[i]) add4(s, po[j][l32]);
                float* p = &pooled[bid[i] * FEAT + c0];
                atomicAdd(p + 0, s.x);
                atomicAdd(p + 1, s.y);
                atomicAdd(p + 2, s.z);
                atomicAdd(p + 3, s.w);
            }
        }
    }
}

// ---- per-graph mean-pool partial sums for raw x (slice 0) ----
__global__ void k_pool(const float* __restrict__ F, const int* __restrict__ batch,
        float* __restrict__ pooled)
{
    int g = blockIdx.x >> 3;
    int chunk = blockIdx.x & 7;
    int c = threadIdx.x;   // 128
    int start = lbound(batch, NN, g);
    int end = lbound(batch, NN, g + 1);
    float acc = 0.f;
    for (int n = start + chunk; n < end; n += 8) acc += F[n * HID + c];
    atomicAdd(&pooled[g * FEAT + c], acc);
}

// ---- classifier + log_softmax ----
__global__ void k_final(const float* __restrict__ pooled, const int* __restrict__ batch,
        const float* __restrict__ Wc, const float* __restrict__ bc, float* __restrict__ out)
{
    __shared__ float lg[NOUT];
    int g = blockIdx.x;
    int t = threadIdx.x;  // 64
    int start = lbound(batch, NN, g);
    int end = lbound(batch, NN, g + 1);
    float inv = 1.f / fmaxf((float)(end - start), 1.f);
    if (t < NOUT) {
        float acc = bc[t];
        for (int c = 0; c < FEAT; ++c)
            acc = fmaf(pooled[g * FEAT + c] * inv, Wc[c * NOUT + t], acc);
        lg[t] = acc;
    }
    __syncthreads();
    if (t == 0) {
        float m = -1e30f;
        for (int o = 0; o < NOUT; ++o) m = fmaxf(m, lg[o]);
        float ssum = 0.f;
        for (int o = 0; o < NOUT; ++o) ssum += expf(lg[o] - m);
        float lse = m + logf(ssum);
        for (int o = 0; o < NOUT; ++o) out[g * NOUT + o] = lg[o] - lse;
    }
}

extern "C" void kernel_launch(void* const* d_in, const int* in_sizes, int n_in,
                              void* d_out, int out_size, void* d_ws, size_t ws_size,
                              hipStream_t stream)
{
    const float* x      = (const float*)d_in[0];
    const int*   ei     = (const int*)d_in[1];
    const int*   batch  = (const int*)d_in[2];
    const float* Ws     = (const float*)d_in[3];
    const float* bs     = (const float*)d_in[4];
    const float* gammas = (const float*)d_in[5];
    const float* betas  = (const float*)d_in[6];
    const float* rms    = (const float*)d_in[7];
    const float* rvs    = (const float*)d_in[8];
    const float* Wc     = (const float*)d_in[9];
    const float* bc     = (const float*)d_in[10];
    float* out = (float*)d_out;

    float* A      = (float*)d_ws;               // NN*HID
    float* B      = A + (size_t)NN * HID;       // NN*HID
    float* dinv   = B + (size_t)NN * HID;       // NN
    float* pooled = dinv + NN;                  // NG*FEAT
    int*   cnt    = (int*)(pooled + NG * FEAT); // NN
    int*   rowptr = cnt + NN;                   // NN+1
    int*   cursor = rowptr + NN + 1;            // NN
    int*   bsum   = cursor + NN;                // NB
    int*   bsumsc = bsum + NB;                  // NB
    int*   csr    = bsumsc + NB;                // NE

    hipMemsetAsync(cnt, 0, NN * sizeof(int), stream);
    hipMemsetAsync(pooled, 0, NG * FEAT * sizeof(float), stream);

    // CSR build (once; reused for all 3 layers)
    k_count<<<(NE + 255) / 256, 256, 0, stream>>>(ei, cnt);
    k_dinv<<<(NN + 255) / 256, 256, 0, stream>>>(cnt, dinv);
    k_bsum<<<NB, 256, 0, stream>>>(cnt, bsum);
    k_bscan<<<1, 64, 0, stream>>>(bsum, bsumsc, rowptr);
    k_scan<<<NB, 256, 0, stream>>>(cnt, bsumsc, rowptr, cursor);
    k_fill<<<(NE + 255) / 256, 256, 0, stream>>>(ei, cursor, csr);

    // pool raw x into slice 0
    k_pool<<<NG * 8, 128, 0, stream>>>(x, batch, pooled + 0);

    const float* H = x;
    for (int L = 0; L < 3; ++L) {
        k_gemm<<<512, 256, 0, stream>>>(H, Ws + (size_t)L * HID * HID, dinv, A);
        k_agg<<<NN / 8, 256, 0, stream>>>(A, rowptr, csr, dinv,
            bs + L * HID, gammas + L * HID, betas + L * HID,
            rms + L * HID, rvs + L * HID,
            batch, pooled + (L + 1) * HID, B);
        H = B;
    }

    k_final<<<NG, 64, 0, stream>>>(pooled, batch, Wc, bc, out);
}

// Round 6
// 378.939 us; speedup vs baseline: 3.4650x; 1.2490x over previous
//
#include <hip/hip_runtime.h>

#define NN 50000
#define NE 800000
#define HID 128
#define NG 128
#define NOUT 10
#define FEAT 512   // 128*3 + 128
#define BN_EPS 1e-5f
#define NB ((NN + 255) / 256)   // 196 scan blocks

__device__ __forceinline__ void fma4(float4& acc, float s, const float4& v) {
    acc.x = fmaf(s, v.x, acc.x);
    acc.y = fmaf(s, v.y, acc.y);
    acc.z = fmaf(s, v.z, acc.z);
    acc.w = fmaf(s, v.w, acc.w);
}
__device__ __forceinline__ void add4(float4& a, const float4& v) {
    a.x += v.x; a.y += v.y; a.z += v.z; a.w += v.w;
}
// f32 -> bf16 with round-to-nearest-even
__device__ __forceinline__ unsigned short f2bf(float f) {
    unsigned int u = __float_as_uint(f);
    u += 0x7FFFu + ((u >> 16) & 1u);
    return (unsigned short)(u >> 16);
}
// bf16 (as u16) -> f32
__device__ __forceinline__ float bf2f(unsigned int h) {
    return __uint_as_float(h << 16);
}

__device__ __forceinline__ int lbound(const int* __restrict__ b, int n, int v) {
    int lo = 0, hi = n;
    while (lo < hi) { int mid = (lo + hi) >> 1; if (b[mid] < v) lo = mid + 1; else hi = mid; }
    return lo;
}

// ---- CSR build ----
__global__ void k_count(const int* __restrict__ ei, int* __restrict__ cnt) {
    int e = blockIdx.x * 256 + threadIdx.x;
    if (e < NE) atomicAdd(&cnt[ei[NE + e]], 1);
}
__global__ void k_dinv(const int* __restrict__ cnt, float* __restrict__ dinv) {
    int i = blockIdx.x * 256 + threadIdx.x;
    if (i < NN) dinv[i] = rsqrtf((float)cnt[i] + 1.0f);   // +1 self-loop
}
__global__ void k_bsum(const int* __restrict__ cnt, int* __restrict__ bsum) {
    __shared__ int sh[256];
    int i = blockIdx.x * 256 + threadIdx.x;
    sh[threadIdx.x] = (i < NN) ? cnt[i] : 0;
    __syncthreads();
    for (int off = 128; off > 0; off >>= 1) {
        if (threadIdx.x < off) sh[threadIdx.x] += sh[threadIdx.x + off];
        __syncthreads();
    }
    if (threadIdx.x == 0) bsum[blockIdx.x] = sh[0];
}
__global__ void k_bscan(const int* __restrict__ bsum, int* __restrict__ bsumsc,
                        int* __restrict__ rowptr) {
    if (threadIdx.x == 0) {
        int run = 0;
        for (int b = 0; b < NB; ++b) { bsumsc[b] = run; run += bsum[b]; }
        rowptr[NN] = NE;
    }
}
__global__ void k_scan(const int* __restrict__ cnt, const int* __restrict__ bsumsc,
                       int* __restrict__ rowptr, int* __restrict__ cursor) {
    __shared__ int sh[256];
    int t = threadIdx.x;
    int i = blockIdx.x * 256 + t;
    int v = (i < NN) ? cnt[i] : 0;
    sh[t] = v;
    __syncthreads();
    for (int off = 1; off < 256; off <<= 1) {
        int add = (t >= off) ? sh[t - off] : 0;
        __syncthreads();
        sh[t] += add;
        __syncthreads();
    }
    if (i < NN) {
        int excl = sh[t] - v + bsumsc[blockIdx.x];
        rowptr[i] = excl;
        cursor[i] = excl;
    }
}
__global__ void k_fill(const int* __restrict__ ei, int* __restrict__ cursor,
                       int* __restrict__ csr) {
    int e = blockIdx.x * 256 + threadIdx.x;
    if (e < NE) {
        int pos = atomicAdd(&cursor[ei[NE + e]], 1);
        csr[pos] = ei[e];   // src
    }
}

// ---- per-row GEMM: A_bf16[row,:] = bf16((H[row,:] @ W) * dinv[row]) ----
__global__ __launch_bounds__(256) void k_gemm(const float* __restrict__ H,
        const float* __restrict__ Wg, const float* __restrict__ dinv,
        unsigned short* __restrict__ Ab)
{
    __shared__ __align__(16) float wl[HID * HID];   // 64 KB
    __shared__ __align__(16) float hl[16 * 132];
    const int tid = threadIdx.x;
#pragma unroll
    for (int i = 0; i < 16; ++i) {
        int flat = (i * 256 + tid) * 4;
        *(float4*)&wl[flat] = *(const float4*)&Wg[flat];
    }
    const int cg = (tid & 31) * 4;
    const int r0 = tid >> 5;

    for (int base = blockIdx.x * 16; base < NN; base += gridDim.x * 16) {
        __syncthreads();
#pragma unroll
        for (int j = 0; j < 2; ++j) {
            int flat = (j * 256 + tid) * 4;
            int r = flat >> 7, k = flat & 127;
            int row = base + r;
            float4 v = make_float4(0.f, 0.f, 0.f, 0.f);
            if (row < NN) v = *(const float4*)&H[row * HID + k];
            *(float4*)&hl[r * 132 + k] = v;
        }
        __syncthreads();
        float4 a0 = make_float4(0.f,0.f,0.f,0.f);
        float4 a1 = make_float4(0.f,0.f,0.f,0.f);
#pragma unroll 8
        for (int k = 0; k < HID; k += 4) {
            float4 ha = *(const float4*)&hl[r0 * 132 + k];
            float4 hb = *(const float4*)&hl[(r0 + 8) * 132 + k];
            float4 w0 = *(const float4*)&wl[(k + 0) * HID + cg];
            float4 w1 = *(const float4*)&wl[(k + 1) * HID + cg];
            float4 w2 = *(const float4*)&wl[(k + 2) * HID + cg];
            float4 w3 = *(const float4*)&wl[(k + 3) * HID + cg];
            fma4(a0, ha.x, w0); fma4(a0, ha.y, w1); fma4(a0, ha.z, w2); fma4(a0, ha.w, w3);
            fma4(a1, hb.x, w0); fma4(a1, hb.y, w1); fma4(a1, hb.z, w2); fma4(a1, hb.w, w3);
        }
        int row0 = base + r0, row1 = base + r0 + 8;
        if (row0 < NN) {
            float s = dinv[row0];
            ushort4 o;
            o.x = f2bf(a0.x * s); o.y = f2bf(a0.y * s);
            o.z = f2bf(a0.z * s); o.w = f2bf(a0.w * s);
            *(ushort4*)&Ab[row0 * HID + cg] = o;
        }
        if (row1 < NN) {
            float s = dinv[row1];
            ushort4 o;
            o.x = f2bf(a1.x * s); o.y = f2bf(a1.y * s);
            o.z = f2bf(a1.z * s); o.w = f2bf(a1.w * s);
            *(ushort4*)&Ab[row1 * HID + cg] = o;
        }
    }
}

// ---- pull aggregation (bf16 A) + fused BN+ReLU + fused pool ----
// 16 lanes per row (uint4 = 8 bf16 ch/lane), 4 nodes/wave, edge-unroll x4
// -> 16 rows (4 KB) in flight per wave.
__global__ __launch_bounds__(256) void k_agg(const unsigned short* __restrict__ Ab,
        const int* __restrict__ rowptr, const int* __restrict__ csr,
        const float* __restrict__ dinv, const float* __restrict__ bs,
        const float* __restrict__ gam, const float* __restrict__ bet,
        const float* __restrict__ rm, const float* __restrict__ rv,
        const int* __restrict__ batch, float* __restrict__ pooled,
        float* __restrict__ B)
{
    const int w = threadIdx.x >> 6;
    const int lane = threadIdx.x & 63;
    const int grp = lane >> 4;               // 4 node-groups per wave
    const int l16 = lane & 15;
    const int nloc = w * 4 + grp;            // node within block 0..15
    const int d = blockIdx.x * 16 + nloc;    // 3125 blocks cover NN exactly
    const uint4* __restrict__ A4 = (const uint4*)Ab;   // row stride = 16 uint4

    float acc[8];
    {
        uint4 v = A4[d * 16 + l16];          // self-loop term
        acc[0] = bf2f(v.x & 0xFFFFu); acc[1] = bf2f(v.x >> 16);
        acc[2] = bf2f(v.y & 0xFFFFu); acc[3] = bf2f(v.y >> 16);
        acc[4] = bf2f(v.z & 0xFFFFu); acc[5] = bf2f(v.z >> 16);
        acc[6] = bf2f(v.w & 0xFFFFu); acc[7] = bf2f(v.w >> 16);
    }
    int e = rowptr[d], e1 = rowptr[d + 1];
    for (; e + 3 < e1; e += 4) {
        int4 s4 = *(const int4*)&csr[e];
        uint4 v0 = A4[s4.x * 16 + l16];
        uint4 v1 = A4[s4.y * 16 + l16];
        uint4 v2 = A4[s4.z * 16 + l16];
        uint4 v3 = A4[s4.w * 16 + l16];
        acc[0] += bf2f(v0.x & 0xFFFFu); acc[1] += bf2f(v0.x >> 16);
        acc[2] += bf2f(v0.y & 0xFFFFu); acc[3] += bf2f(v0.y >> 16);
        acc[4] += bf2f(v0.z & 0xFFFFu); acc[5] += bf2f(v0.z >> 16);
        acc[6] += bf2f(v0.w & 0xFFFFu); acc[7] += bf2f(v0.w >> 16);
        acc[0] += bf2f(v1.x & 0xFFFFu); acc[1] += bf2f(v1.x >> 16);
        acc[2] += bf2f(v1.y & 0xFFFFu); acc[3] += bf2f(v1.y >> 16);
        acc[4] += bf2f(v1.z & 0xFFFFu); acc[5] += bf2f(v1.z >> 16);
        acc[6] += bf2f(v1.w & 0xFFFFu); acc[7] += bf2f(v1.w >> 16);
        acc[0] += bf2f(v2.x & 0xFFFFu); acc[1] += bf2f(v2.x >> 16);
        acc[2] += bf2f(v2.y & 0xFFFFu); acc[3] += bf2f(v2.y >> 16);
        acc[4] += bf2f(v2.z & 0xFFFFu); acc[5] += bf2f(v2.z >> 16);
        acc[6] += bf2f(v2.w & 0xFFFFu); acc[7] += bf2f(v2.w >> 16);
        acc[0] += bf2f(v3.x & 0xFFFFu); acc[1] += bf2f(v3.x >> 16);
        acc[2] += bf2f(v3.y & 0xFFFFu); acc[3] += bf2f(v3.y >> 16);
        acc[4] += bf2f(v3.z & 0xFFFFu); acc[5] += bf2f(v3.z >> 16);
        acc[6] += bf2f(v3.w & 0xFFFFu); acc[7] += bf2f(v3.w >> 16);
    }
    for (; e < e1; ++e) {
        uint4 v = A4[csr[e] * 16 + l16];
        acc[0] += bf2f(v.x & 0xFFFFu); acc[1] += bf2f(v.x >> 16);
        acc[2] += bf2f(v.y & 0xFFFFu); acc[3] += bf2f(v.y >> 16);
        acc[4] += bf2f(v.z & 0xFFFFu); acc[5] += bf2f(v.z >> 16);
        acc[6] += bf2f(v.w & 0xFFFFu); acc[7] += bf2f(v.w >> 16);
    }

    const int c0 = l16 * 8;
    const float di = dinv[d];
    float o[8];
#pragma unroll
    for (int j = 0; j < 8; ++j) {
        int c = c0 + j;
        float sc = gam[c] * rsqrtf(rv[c] + BN_EPS);
        o[j] = fmaxf((acc[j] * di + bs[c] - rm[c]) * sc + bet[c], 0.f);
    }
    float4 ov0 = make_float4(o[0], o[1], o[2], o[3]);
    float4 ov1 = make_float4(o[4], o[5], o[6], o[7]);
    float4* Bv = (float4*)B;
    Bv[d * 32 + l16 * 2]     = ov0;
    Bv[d * 32 + l16 * 2 + 1] = ov1;

    // block-level pool combine: batch sorted -> 16 nodes usually share a graph
    __shared__ float4 po[16][32];
    __shared__ int bid[16];
    po[nloc][l16 * 2]     = ov0;
    po[nloc][l16 * 2 + 1] = ov1;
    if (l16 == 0) bid[nloc] = batch[d];
    __syncthreads();
    if (threadIdx.x < 32) {   // one 32-lane group handles all channels as float4
        int l32 = threadIdx.x;
#pragma unroll
        for (int i = 0; i < 16; ++i) {
            bool lead = true;
            for (int j = 0; j < i; ++j) lead = lead && (bid[j] != bid[i]);
            if (lead) {
                float4 s = po[i][l32];
                for (int j = i + 1; j < 16; ++j)
                    if (bid[j] == bid[i]) add4(s, po[j][l32]);
                float* p = &pooled[bid[i] * FEAT + l32 * 4];
                atomicAdd(p + 0, s.x);
                atomicAdd(p + 1, s.y);
                atomicAdd(p + 2, s.z);
                atomicAdd(p + 3, s.w);
            }
        }
    }
}

// ---- per-graph mean-pool partial sums for raw x (slice 0) ----
__global__ void k_pool(const float* __restrict__ F, const int* __restrict__ batch,
        float* __restrict__ pooled)
{
    int g = blockIdx.x >> 3;
    int chunk = blockIdx.x & 7;
    int c = threadIdx.x;   // 128
    int start = lbound(batch, NN, g);
    int end = lbound(batch, NN, g + 1);
    float acc = 0.f;
    for (int n = start + chunk; n < end; n += 8) acc += F[n * HID + c];
    atomicAdd(&pooled[g * FEAT + c], acc);
}

// ---- classifier + log_softmax ----
__global__ void k_final(const float* __restrict__ pooled, const int* __restrict__ batch,
        const float* __restrict__ Wc, const float* __restrict__ bc, float* __restrict__ out)
{
    __shared__ float lg[NOUT];
    int g = blockIdx.x;
    int t = threadIdx.x;  // 64
    int start = lbound(batch, NN, g);
    int end = lbound(batch, NN, g + 1);
    float inv = 1.f / fmaxf((float)(end - start), 1.f);
    if (t < NOUT) {
        float acc = bc[t];
        for (int c = 0; c < FEAT; ++c)
            acc = fmaf(pooled[g * FEAT + c] * inv, Wc[c * NOUT + t], acc);
        lg[t] = acc;
    }
    __syncthreads();
    if (t == 0) {
        float m = -1e30f;
        for (int o = 0; o < NOUT; ++o) m = fmaxf(m, lg[o]);
        float ssum = 0.f;
        for (int o = 0; o < NOUT; ++o) ssum += expf(lg[o] - m);
        float lse = m + logf(ssum);
        for (int o = 0; o < NOUT; ++o) out[g * NOUT + o] = lg[o] - lse;
    }
}

extern "C" void kernel_launch(void* const* d_in, const int* in_sizes, int n_in,
                              void* d_out, int out_size, void* d_ws, size_t ws_size,
                              hipStream_t stream)
{
    const float* x      = (const float*)d_in[0];
    const int*   ei     = (const int*)d_in[1];
    const int*   batch  = (const int*)d_in[2];
    const float* Ws     = (const float*)d_in[3];
    const float* bs     = (const float*)d_in[4];
    const float* gammas = (const float*)d_in[5];
    const float* betas  = (const float*)d_in[6];
    const float* rms    = (const float*)d_in[7];
    const float* rvs    = (const float*)d_in[8];
    const float* Wc     = (const float*)d_in[9];
    const float* bc     = (const float*)d_in[10];
    float* out = (float*)d_out;

    float*          B      = (float*)d_ws;                  // NN*HID f32
    unsigned short* Ab     = (unsigned short*)(B + (size_t)NN * HID);  // NN*HID bf16
    float*          dinv   = (float*)(Ab + (size_t)NN * HID);          // NN
    float*          pooled = dinv + NN;                     // NG*FEAT
    int*            cnt    = (int*)(pooled + NG * FEAT);    // NN
    int*            rowptr = cnt + NN;                      // NN+1
    int*            cursor = rowptr + NN + 1;               // NN
    int*            bsum   = cursor + NN;                   // NB
    int*            bsumsc = bsum + NB;                     // NB
    int*            csr    = bsumsc + NB;                   // NE

    hipMemsetAsync(cnt, 0, NN * sizeof(int), stream);
    hipMemsetAsync(pooled, 0, NG * FEAT * sizeof(float), stream);

    // CSR build (once; reused for all 3 layers)
    k_count<<<(NE + 255) / 256, 256, 0, stream>>>(ei, cnt);
    k_dinv<<<(NN + 255) / 256, 256, 0, stream>>>(cnt, dinv);
    k_bsum<<<NB, 256, 0, stream>>>(cnt, bsum);
    k_bscan<<<1, 64, 0, stream>>>(bsum, bsumsc, rowptr);
    k_scan<<<NB, 256, 0, stream>>>(cnt, bsumsc, rowptr, cursor);
    k_fill<<<(NE + 255) / 256, 256, 0, stream>>>(ei, cursor, csr);

    // pool raw x into slice 0
    k_pool<<<NG * 8, 128, 0, stream>>>(x, batch, pooled + 0);

    const float* H = x;
    for (int L = 0; L < 3; ++L) {
        k_gemm<<<512, 256, 0, stream>>>(H, Ws + (size_t)L * HID * HID, dinv, Ab);
        k_agg<<<NN / 16, 256, 0, stream>>>(Ab, rowptr, csr, dinv,
            bs + L * HID, gammas + L * HID, betas + L * HID,
            rms + L * HID, rvs + L * HID,
            batch, pooled + (L + 1) * HID, B);
        H = B;
    }

    k_final<<<NG, 64, 0, stream>>>(pooled, batch, Wc, bc, out);
}

// Round 7
// 361.433 us; speedup vs baseline: 3.6328x; 1.0484x over previous
//
#include <hip/hip_runtime.h>

#define NN 50000
#define NE 800000
#define HID 128
#define NG 128
#define NOUT 10
#define FEAT 512   // 128*3 + 128
#define BN_EPS 1e-5f
#define NB ((NN + 255) / 256)   // 196 scan blocks
#define NTILE (NN / 16)         // 3125 row-tiles for MFMA gemm

typedef __attribute__((ext_vector_type(8))) short bf16x8;
typedef __attribute__((ext_vector_type(4))) float f32x4;

__device__ __forceinline__ void add4(float4& a, const float4& v) {
    a.x += v.x; a.y += v.y; a.z += v.z; a.w += v.w;
}
// f32 -> bf16 round-to-nearest-even
__device__ __forceinline__ unsigned short f2bf(float f) {
    unsigned int u = __float_as_uint(f);
    u += 0x7FFFu + ((u >> 16) & 1u);
    return (unsigned short)(u >> 16);
}
__device__ __forceinline__ float bf2f(unsigned int h) {
    return __uint_as_float(h << 16);
}

__device__ __forceinline__ int lbound(const int* __restrict__ b, int n, int v) {
    int lo = 0, hi = n;
    while (lo < hi) { int mid = (lo + hi) >> 1; if (b[mid] < v) lo = mid + 1; else hi = mid; }
    return lo;
}

// ---- CSR build ----
__global__ void k_count(const int* __restrict__ ei, int* __restrict__ cnt) {
    int e = blockIdx.x * 256 + threadIdx.x;
    if (e < NE) atomicAdd(&cnt[ei[NE + e]], 1);
}
__global__ void k_dinv(const int* __restrict__ cnt, float* __restrict__ dinv) {
    int i = blockIdx.x * 256 + threadIdx.x;
    if (i < NN) dinv[i] = rsqrtf((float)cnt[i] + 1.0f);   // +1 self-loop
}
__global__ void k_bsum(const int* __restrict__ cnt, int* __restrict__ bsum) {
    __shared__ int sh[256];
    int i = blockIdx.x * 256 + threadIdx.x;
    sh[threadIdx.x] = (i < NN) ? cnt[i] : 0;
    __syncthreads();
    for (int off = 128; off > 0; off >>= 1) {
        if (threadIdx.x < off) sh[threadIdx.x] += sh[threadIdx.x + off];
        __syncthreads();
    }
    if (threadIdx.x == 0) bsum[blockIdx.x] = sh[0];
}
__global__ void k_bscan(const int* __restrict__ bsum, int* __restrict__ bsumsc,
                        int* __restrict__ rowptr) {
    if (threadIdx.x == 0) {
        int run = 0;
        for (int b = 0; b < NB; ++b) { bsumsc[b] = run; run += bsum[b]; }
        rowptr[NN] = NE;
    }
}
__global__ void k_scan(const int* __restrict__ cnt, const int* __restrict__ bsumsc,
                       int* __restrict__ rowptr, int* __restrict__ cursor) {
    __shared__ int sh[256];
    int t = threadIdx.x;
    int i = blockIdx.x * 256 + t;
    int v = (i < NN) ? cnt[i] : 0;
    sh[t] = v;
    __syncthreads();
    for (int off = 1; off < 256; off <<= 1) {
        int add = (t >= off) ? sh[t - off] : 0;
        __syncthreads();
        sh[t] += add;
        __syncthreads();
    }
    if (i < NN) {
        int excl = sh[t] - v + bsumsc[blockIdx.x];
        rowptr[i] = excl;
        cursor[i] = excl;
    }
}
__global__ void k_fill(const int* __restrict__ ei, int* __restrict__ cursor,
                       int* __restrict__ csr) {
    int e = blockIdx.x * 256 + threadIdx.x;
    if (e < NE) {
        int pos = atomicAdd(&cursor[ei[NE + e]], 1);
        csr[pos] = ei[e];   // src
    }
}

// ---- converts ----
// x fp32 -> bf16 (8 elems/thread)
__global__ void k_cvt_x(const float* __restrict__ x, unsigned short* __restrict__ xb) {
    int g = blockIdx.x * 256 + threadIdx.x;      // 800000 threads
    const float4* xv = (const float4*)x;
    float4 a = xv[g * 2], b = xv[g * 2 + 1];
    ushort4 o0, o1;
    o0.x = f2bf(a.x); o0.y = f2bf(a.y); o0.z = f2bf(a.z); o0.w = f2bf(a.w);
    o1.x = f2bf(b.x); o1.y = f2bf(b.y); o1.z = f2bf(b.z); o1.w = f2bf(b.w);
    *(ushort4*)&xb[g * 8]     = o0;
    *(ushort4*)&xb[g * 8 + 4] = o1;
}
// W[L][k][c] fp32 -> Wt[L][c][k] bf16 (all 3 layers)
__global__ void k_cvt_w(const float* __restrict__ Ws, unsigned short* __restrict__ Wt) {
    int g = blockIdx.x * 256 + threadIdx.x;      // 49152 threads
    int l = g >> 14, rem = g & 16383;
    int c = rem >> 7, k = rem & 127;
    Wt[g] = f2bf(Ws[l * 16384 + k * 128 + c]);
}

// ---- MFMA GEMM: Ab[row,:] = bf16( (Hb[row,:] @ W) * dinv[row] ) ----
// One wave per 16x128 tile. A-frags direct from global; B-frags from L1-resident Wt.
// A/B use identical per-lane k-mapping (k-permutation invariant); C/D layout per m89:
// col = lane&15, row = (lane>>4)*4 + reg.
__global__ __launch_bounds__(256) void k_gemm_mfma(
        const unsigned short* __restrict__ Hb,   // [NN][128] bf16
        const unsigned short* __restrict__ Wt,   // [128][128] bf16, Wt[c][k]
        const float* __restrict__ dinv,
        unsigned short* __restrict__ Ab)
{
    const int w = threadIdx.x >> 6;
    const int l = threadIdx.x & 63;
    const int lr = l & 15;          // A-row / B-col / D-col
    const int kg = l >> 4;          // k-group
    const int tile = blockIdx.x * 4 + w;
    if (tile >= NTILE) return;
    const int rbase = tile * 16;

    bf16x8 af[4];
    const unsigned short* hrow = Hb + (size_t)(rbase + lr) * HID + kg * 8;
#pragma unroll
    for (int s = 0; s < 4; ++s)
        af[s] = *(const bf16x8*)(hrow + s * 32);

    const float4 dv = *(const float4*)&dinv[rbase + kg * 4];
    const float dvj[4] = {dv.x, dv.y, dv.z, dv.w};

#pragma unroll
    for (int ct = 0; ct < 8; ++ct) {
        const unsigned short* wrow = Wt + (size_t)(ct * 16 + lr) * HID + kg * 8;
        f32x4 acc = {0.f, 0.f, 0.f, 0.f};
#pragma unroll
        for (int s = 0; s < 4; ++s) {
            bf16x8 bf = *(const bf16x8*)(wrow + s * 32);
            acc = __builtin_amdgcn_mfma_f32_16x16x32_bf16(af[s], bf, acc, 0, 0, 0);
        }
#pragma unroll
        for (int j = 0; j < 4; ++j) {
            float v = acc[j] * dvj[j];
            Ab[(size_t)(rbase + kg * 4 + j) * HID + ct * 16 + lr] = f2bf(v);
        }
    }
}

// ---- pull aggregation (bf16 A) + fused BN+ReLU + fused pool; B stored bf16 ----
__global__ __launch_bounds__(256) void k_agg(const unsigned short* __restrict__ Ab,
        const int* __restrict__ rowptr, const int* __restrict__ csr,
        const float* __restrict__ dinv, const float* __restrict__ bs,
        const float* __restrict__ gam, const float* __restrict__ bet,
        const float* __restrict__ rm, const float* __restrict__ rv,
        const int* __restrict__ batch, float* __restrict__ pooled,
        unsigned short* __restrict__ Bb)
{
    const int w = threadIdx.x >> 6;
    const int lane = threadIdx.x & 63;
    const int grp = lane >> 4;               // 4 node-groups per wave
    const int l16 = lane & 15;
    const int nloc = w * 4 + grp;            // node within block 0..15
    const int d = blockIdx.x * 16 + nloc;    // 3125 blocks cover NN exactly
    const uint4* __restrict__ A4 = (const uint4*)Ab;   // row stride = 16 uint4

    float acc[8];
    {
        uint4 v = A4[d * 16 + l16];          // self-loop term
        acc[0] = bf2f(v.x & 0xFFFFu); acc[1] = bf2f(v.x >> 16);
        acc[2] = bf2f(v.y & 0xFFFFu); acc[3] = bf2f(v.y >> 16);
        acc[4] = bf2f(v.z & 0xFFFFu); acc[5] = bf2f(v.z >> 16);
        acc[6] = bf2f(v.w & 0xFFFFu); acc[7] = bf2f(v.w >> 16);
    }
    int e = rowptr[d], e1 = rowptr[d + 1];
    for (; e + 3 < e1; e += 4) {
        int4 s4 = *(const int4*)&csr[e];
        uint4 v0 = A4[s4.x * 16 + l16];
        uint4 v1 = A4[s4.y * 16 + l16];
        uint4 v2 = A4[s4.z * 16 + l16];
        uint4 v3 = A4[s4.w * 16 + l16];
        acc[0] += bf2f(v0.x & 0xFFFFu); acc[1] += bf2f(v0.x >> 16);
        acc[2] += bf2f(v0.y & 0xFFFFu); acc[3] += bf2f(v0.y >> 16);
        acc[4] += bf2f(v0.z & 0xFFFFu); acc[5] += bf2f(v0.z >> 16);
        acc[6] += bf2f(v0.w & 0xFFFFu); acc[7] += bf2f(v0.w >> 16);
        acc[0] += bf2f(v1.x & 0xFFFFu); acc[1] += bf2f(v1.x >> 16);
        acc[2] += bf2f(v1.y & 0xFFFFu); acc[3] += bf2f(v1.y >> 16);
        acc[4] += bf2f(v1.z & 0xFFFFu); acc[5] += bf2f(v1.z >> 16);
        acc[6] += bf2f(v1.w & 0xFFFFu); acc[7] += bf2f(v1.w >> 16);
        acc[0] += bf2f(v2.x & 0xFFFFu); acc[1] += bf2f(v2.x >> 16);
        acc[2] += bf2f(v2.y & 0xFFFFu); acc[3] += bf2f(v2.y >> 16);
        acc[4] += bf2f(v2.z & 0xFFFFu); acc[5] += bf2f(v2.z >> 16);
        acc[6] += bf2f(v2.w & 0xFFFFu); acc[7] += bf2f(v2.w >> 16);
        acc[0] += bf2f(v3.x & 0xFFFFu); acc[1] += bf2f(v3.x >> 16);
        acc[2] += bf2f(v3.y & 0xFFFFu); acc[3] += bf2f(v3.y >> 16);
        acc[4] += bf2f(v3.z & 0xFFFFu); acc[5] += bf2f(v3.z >> 16);
        acc[6] += bf2f(v3.w & 0xFFFFu); acc[7] += bf2f(v3.w >> 16);
    }
    for (; e < e1; ++e) {
        uint4 v = A4[csr[e] * 16 + l16];
        acc[0] += bf2f(v.x & 0xFFFFu); acc[1] += bf2f(v.x >> 16);
        acc[2] += bf2f(v.y & 0xFFFFu); acc[3] += bf2f(v.y >> 16);
        acc[4] += bf2f(v.z & 0xFFFFu); acc[5] += bf2f(v.z >> 16);
        acc[6] += bf2f(v.w & 0xFFFFu); acc[7] += bf2f(v.w >> 16);
    }

    const int c0 = l16 * 8;
    const float di = dinv[d];
    float o[8];
#pragma unroll
    for (int j = 0; j < 8; ++j) {
        int c = c0 + j;
        float sc = gam[c] * rsqrtf(rv[c] + BN_EPS);
        o[j] = fmaxf((acc[j] * di + bs[c] - rm[c]) * sc + bet[c], 0.f);
    }
    // store B as bf16 (next layer's MFMA input)
    uint4 ob;
    ob.x = (unsigned)f2bf(o[0]) | ((unsigned)f2bf(o[1]) << 16);
    ob.y = (unsigned)f2bf(o[2]) | ((unsigned)f2bf(o[3]) << 16);
    ob.z = (unsigned)f2bf(o[4]) | ((unsigned)f2bf(o[5]) << 16);
    ob.w = (unsigned)f2bf(o[6]) | ((unsigned)f2bf(o[7]) << 16);
    ((uint4*)Bb)[d * 16 + l16] = ob;

    // block-level pool combine (fp32 path)
    __shared__ float4 po[16][32];
    __shared__ int bid[16];
    po[nloc][l16 * 2]     = make_float4(o[0], o[1], o[2], o[3]);
    po[nloc][l16 * 2 + 1] = make_float4(o[4], o[5], o[6], o[7]);
    if (l16 == 0) bid[nloc] = batch[d];
    __syncthreads();
    if (threadIdx.x < 32) {
        int l32 = threadIdx.x;
#pragma unroll
        for (int i = 0; i < 16; ++i) {
            bool lead = true;
            for (int j = 0; j < i; ++j) lead = lead && (bid[j] != bid[i]);
            if (lead) {
                float4 s = po[i][l32];
                for (int j = i + 1; j < 16; ++j)
                    if (bid[j] == bid[i]) add4(s, po[j][l32]);
                float* p = &pooled[bid[i] * FEAT + l32 * 4];
                atomicAdd(p + 0, s.x);
                atomicAdd(p + 1, s.y);
                atomicAdd(p + 2, s.z);
                atomicAdd(p + 3, s.w);
            }
        }
    }
}

// ---- per-graph mean-pool partial sums for raw x (slice 0) ----
__global__ void k_pool(const float* __restrict__ F, const int* __restrict__ batch,
        float* __restrict__ pooled)
{
    int g = blockIdx.x >> 3;
    int chunk = blockIdx.x & 7;
    int c = threadIdx.x;   // 128
    int start = lbound(batch, NN, g);
    int end = lbound(batch, NN, g + 1);
    float acc = 0.f;
    for (int n = start + chunk; n < end; n += 8) acc += F[n * HID + c];
    atomicAdd(&pooled[g * FEAT + c], acc);
}

// ---- classifier + log_softmax ----
__global__ void k_final(const float* __restrict__ pooled, const int* __restrict__ batch,
        const float* __restrict__ Wc, const float* __restrict__ bc, float* __restrict__ out)
{
    __shared__ float lg[NOUT];
    int g = blockIdx.x;
    int t = threadIdx.x;  // 64
    int start = lbound(batch, NN, g);
    int end = lbound(batch, NN, g + 1);
    float inv = 1.f / fmaxf((float)(end - start), 1.f);
    if (t < NOUT) {
        float acc = bc[t];
        for (int c = 0; c < FEAT; ++c)
            acc = fmaf(pooled[g * FEAT + c] * inv, Wc[c * NOUT + t], acc);
        lg[t] = acc;
    }
    __syncthreads();
    if (t == 0) {
        float m = -1e30f;
        for (int o = 0; o < NOUT; ++o) m = fmaxf(m, lg[o]);
        float ssum = 0.f;
        for (int o = 0; o < NOUT; ++o) ssum += expf(lg[o] - m);
        float lse = m + logf(ssum);
        for (int o = 0; o < NOUT; ++o) out[g * NOUT + o] = lg[o] - lse;
    }
}

extern "C" void kernel_launch(void* const* d_in, const int* in_sizes, int n_in,
                              void* d_out, int out_size, void* d_ws, size_t ws_size,
                              hipStream_t stream)
{
    const float* x      = (const float*)d_in[0];
    const int*   ei     = (const int*)d_in[1];
    const int*   batch  = (const int*)d_in[2];
    const float* Ws     = (const float*)d_in[3];
    const float* bs     = (const float*)d_in[4];
    const float* gammas = (const float*)d_in[5];
    const float* betas  = (const float*)d_in[6];
    const float* rms    = (const float*)d_in[7];
    const float* rvs    = (const float*)d_in[8];
    const float* Wc     = (const float*)d_in[9];
    const float* bc     = (const float*)d_in[10];
    float* out = (float*)d_out;

    float*          dinv   = (float*)d_ws;                     // NN
    float*          pooled = dinv + NN;                        // NG*FEAT
    unsigned short* Bb     = (unsigned short*)(pooled + NG * FEAT);    // NN*HID bf16
    unsigned short* Ab     = Bb + (size_t)NN * HID;            // NN*HID bf16
    unsigned short* xb     = Ab + (size_t)NN * HID;            // NN*HID bf16
    unsigned short* Wt     = xb + (size_t)NN * HID;            // 3*HID*HID bf16
    int*            cnt    = (int*)(Wt + 3 * HID * HID);       // NN
    int*            rowptr = cnt + NN;                         // NN+1
    int*            cursor = rowptr + NN + 1;                  // NN
    int*            bsum   = cursor + NN;                      // NB
    int*            bsumsc = bsum + NB;                        // NB
    int*            csr    = bsumsc + NB;                      // NE

    hipMemsetAsync(cnt, 0, NN * sizeof(int), stream);
    hipMemsetAsync(pooled, 0, NG * FEAT * sizeof(float), stream);

    // CSR build (once; reused for all 3 layers)
    k_count<<<(NE + 255) / 256, 256, 0, stream>>>(ei, cnt);
    k_dinv<<<(NN + 255) / 256, 256, 0, stream>>>(cnt, dinv);
    k_bsum<<<NB, 256, 0, stream>>>(cnt, bsum);
    k_bscan<<<1, 64, 0, stream>>>(bsum, bsumsc, rowptr);
    k_scan<<<NB, 256, 0, stream>>>(cnt, bsumsc, rowptr, cursor);
    k_fill<<<(NE + 255) / 256, 256, 0, stream>>>(ei, cursor, csr);

    // converts
    k_cvt_x<<<(NN * HID / 8 + 255) / 256, 256, 0, stream>>>(x, xb);
    k_cvt_w<<<(3 * HID * HID + 255) / 256, 256, 0, stream>>>(Ws, Wt);

    // pool raw x into slice 0
    k_pool<<<NG * 8, 128, 0, stream>>>(x, batch, pooled + 0);

    const unsigned short* H = xb;
    for (int L = 0; L < 3; ++L) {
        k_gemm_mfma<<<(NTILE + 3) / 4, 256, 0, stream>>>(H, Wt + L * HID * HID, dinv, Ab);
        k_agg<<<NN / 16, 256, 0, stream>>>(Ab, rowptr, csr, dinv,
            bs + L * HID, gammas + L * HID, betas + L * HID,
            rms + L * HID, rvs + L * HID,
            batch, pooled + (L + 1) * HID, Bb);
        H = Bb;
    }

    k_final<<<NG, 64, 0, stream>>>(pooled, batch, Wc, bc, out);
}

// Round 8
// 343.728 us; speedup vs baseline: 3.8199x; 1.0515x over previous
//
#include <hip/hip_runtime.h>

#define NN 50000
#define NE 800000
#define HID 128
#define NG 128
#define NOUT 10
#define FEAT 512   // 128*3 + 128
#define BN_EPS 1e-5f
#define NB ((NN + 255) / 256)   // 196 scan blocks
#define NTILE (NN / 16)         // 3125 row-tiles

typedef __attribute__((ext_vector_type(8))) short bf16x8;
typedef __attribute__((ext_vector_type(4))) float f32x4;

__device__ __forceinline__ void add4(float4& a, const float4& v) {
    a.x += v.x; a.y += v.y; a.z += v.z; a.w += v.w;
}
__device__ __forceinline__ unsigned short f2bf(float f) {
    unsigned int u = __float_as_uint(f);
    u += 0x7FFFu + ((u >> 16) & 1u);
    return (unsigned short)(u >> 16);
}
__device__ __forceinline__ float bf2f(unsigned int h) {
    return __uint_as_float(h << 16);
}
__device__ __forceinline__ int lbound(const int* __restrict__ b, int n, int v) {
    int lo = 0, hi = n;
    while (lo < hi) { int mid = (lo + hi) >> 1; if (b[mid] < v) lo = mid + 1; else hi = mid; }
    return lo;
}

// ---- CSR build ----
__global__ void k_count(const int* __restrict__ ei, int* __restrict__ cnt) {
    int e = blockIdx.x * 256 + threadIdx.x;
    if (e < NE) atomicAdd(&cnt[ei[NE + e]], 1);
}
__global__ void k_bsum(const int* __restrict__ cnt, int* __restrict__ bsum) {
    __shared__ int sh[256];
    int i = blockIdx.x * 256 + threadIdx.x;
    sh[threadIdx.x] = (i < NN) ? cnt[i] : 0;
    __syncthreads();
    for (int off = 128; off > 0; off >>= 1) {
        if (threadIdx.x < off) sh[threadIdx.x] += sh[threadIdx.x + off];
        __syncthreads();
    }
    if (threadIdx.x == 0) bsum[blockIdx.x] = sh[0];
}
__global__ void k_bscan(const int* __restrict__ bsum, int* __restrict__ bsumsc,
                        int* __restrict__ rowptr) {
    if (threadIdx.x == 0) {
        int run = 0;
        for (int b = 0; b < NB; ++b) { bsumsc[b] = run; run += bsum[b]; }
        rowptr[NN] = NE;
    }
}
// scan + dinv fused
__global__ void k_scan(const int* __restrict__ cnt, const int* __restrict__ bsumsc,
                       int* __restrict__ rowptr, int* __restrict__ cursor,
                       float* __restrict__ dinv) {
    __shared__ int sh[256];
    int t = threadIdx.x;
    int i = blockIdx.x * 256 + t;
    int v = (i < NN) ? cnt[i] : 0;
    sh[t] = v;
    __syncthreads();
    for (int off = 1; off < 256; off <<= 1) {
        int add = (t >= off) ? sh[t - off] : 0;
        __syncthreads();
        sh[t] += add;
        __syncthreads();
    }
    if (i < NN) {
        int excl = sh[t] - v + bsumsc[blockIdx.x];
        rowptr[i] = excl;
        cursor[i] = excl;
        dinv[i] = rsqrtf((float)v + 1.0f);   // +1 self-loop
    }
}
// range-split fill (diagnostic: 2 launches of NE/2)
__global__ void k_fill(const int* __restrict__ ei, int* __restrict__ cursor,
                       int* __restrict__ csr, int ebase, int ecnt) {
    int e = ebase + blockIdx.x * 256 + threadIdx.x;
    if (e < ebase + ecnt) {
        int pos = atomicAdd(&cursor[ei[NE + e]], 1);
        csr[pos] = ei[e];   // src
    }
}

// ---- fused: x->bf16 convert + x mean-pool partials (slice 0), plus W transpose->bf16 ----
__global__ __launch_bounds__(256) void k_cvtx_pool(const float* __restrict__ x,
        const int* __restrict__ batch, const float* __restrict__ Ws,
        unsigned short* __restrict__ xb, unsigned short* __restrict__ Wt,
        float* __restrict__ pooled)
{
    if (blockIdx.x < NN / 16) {
        const int t = threadIdx.x;
        const int nloc = t >> 4;            // 16 nodes per block
        const int l16 = t & 15;             // 8 channels per thread
        const int n = blockIdx.x * 16 + nloc;
        const float4* xr = (const float4*)(x + (size_t)n * HID + l16 * 8);
        float4 a = xr[0], b = xr[1];
        uint4 ob;
        ob.x = (unsigned)f2bf(a.x) | ((unsigned)f2bf(a.y) << 16);
        ob.y = (unsigned)f2bf(a.z) | ((unsigned)f2bf(a.w) << 16);
        ob.z = (unsigned)f2bf(b.x) | ((unsigned)f2bf(b.y) << 16);
        ob.w = (unsigned)f2bf(b.z) | ((unsigned)f2bf(b.w) << 16);
        ((uint4*)xb)[n * 16 + l16] = ob;

        __shared__ float4 po[16][32];
        __shared__ int bid[16];
        po[nloc][l16 * 2]     = a;
        po[nloc][l16 * 2 + 1] = b;
        if (l16 == 0) bid[nloc] = batch[n];
        __syncthreads();
        if (t < 32) {
            int l32 = t;
#pragma unroll
            for (int i = 0; i < 16; ++i) {
                bool lead = true;
                for (int j = 0; j < i; ++j) lead = lead && (bid[j] != bid[i]);
                if (lead) {
                    float4 s = po[i][l32];
                    for (int j = i + 1; j < 16; ++j)
                        if (bid[j] == bid[i]) add4(s, po[j][l32]);
                    float* p = &pooled[bid[i] * FEAT + l32 * 4];
                    atomicAdd(p + 0, s.x);
                    atomicAdd(p + 1, s.y);
                    atomicAdd(p + 2, s.z);
                    atomicAdd(p + 3, s.w);
                }
            }
        }
    } else {
        // W[L][k][c] -> Wt[L][c][k] bf16 : 49152 elems over 24 blocks * 256 * 8
        int g0 = (blockIdx.x - NN / 16) * 2048 + threadIdx.x * 8;
#pragma unroll
        for (int j = 0; j < 8; ++j) {
            int idx = g0 + j;
            int l = idx >> 14, rem = idx & 16383;
            int c = rem >> 7, k = rem & 127;
            Wt[idx] = f2bf(Ws[l * 16384 + k * 128 + c]);
        }
    }
}

// ---- MFMA GEMM: Ab[row,:] = bf16( (Hb[row,:] @ W) * dinv[row] ) ----
__global__ __launch_bounds__(256) void k_gemm_mfma(
        const unsigned short* __restrict__ Hb,   // [NN][128] bf16
        const unsigned short* __restrict__ Wt,   // [128][128] bf16, Wt[c][k]
        const float* __restrict__ dinv,
        unsigned short* __restrict__ Ab)
{
    const int w = threadIdx.x >> 6;
    const int l = threadIdx.x & 63;
    const int lr = l & 15;          // A-row / B-col / D-col
    const int kg = l >> 4;          // k-group
    const int tile = blockIdx.x * 4 + w;
    if (tile >= NTILE) return;
    const int rbase = tile * 16;

    bf16x8 af[4];
    const unsigned short* hrow = Hb + (size_t)(rbase + lr) * HID + kg * 8;
#pragma unroll
    for (int s = 0; s < 4; ++s)
        af[s] = *(const bf16x8*)(hrow + s * 32);

    const float4 dv = *(const float4*)&dinv[rbase + kg * 4];
    const float dvj[4] = {dv.x, dv.y, dv.z, dv.w};

#pragma unroll
    for (int ct = 0; ct < 8; ++ct) {
        const unsigned short* wrow = Wt + (size_t)(ct * 16 + lr) * HID + kg * 8;
        f32x4 acc = {0.f, 0.f, 0.f, 0.f};
#pragma unroll
        for (int s = 0; s < 4; ++s) {
            bf16x8 bf = *(const bf16x8*)(wrow + s * 32);
            acc = __builtin_amdgcn_mfma_f32_16x16x32_bf16(af[s], bf, acc, 0, 0, 0);
        }
#pragma unroll
        for (int j = 0; j < 4; ++j) {
            float v = acc[j] * dvj[j];
            Ab[(size_t)(rbase + kg * 4 + j) * HID + ct * 16 + lr] = f2bf(v);
        }
    }
}

// ---- pull aggregation (bf16 A) + fused BN+ReLU + fused pool; B stored bf16 ----
__global__ __launch_bounds__(256) void k_agg(const unsigned short* __restrict__ Ab,
        const int* __restrict__ rowptr, const int* __restrict__ csr,
        const float* __restrict__ dinv, const float* __restrict__ bs,
        const float* __restrict__ gam, const float* __restrict__ bet,
        const float* __restrict__ rm, const float* __restrict__ rv,
        const int* __restrict__ batch, float* __restrict__ pooled,
        unsigned short* __restrict__ Bb, int writeB)
{
    const int w = threadIdx.x >> 6;
    const int lane = threadIdx.x & 63;
    const int grp = lane >> 4;
    const int l16 = lane & 15;
    const int nloc = w * 4 + grp;
    const int d = blockIdx.x * 16 + nloc;
    const uint4* __restrict__ A4 = (const uint4*)Ab;

    float acc[8];
    {
        uint4 v = A4[d * 16 + l16];          // self-loop term
        acc[0] = bf2f(v.x & 0xFFFFu); acc[1] = bf2f(v.x >> 16);
        acc[2] = bf2f(v.y & 0xFFFFu); acc[3] = bf2f(v.y >> 16);
        acc[4] = bf2f(v.z & 0xFFFFu); acc[5] = bf2f(v.z >> 16);
        acc[6] = bf2f(v.w & 0xFFFFu); acc[7] = bf2f(v.w >> 16);
    }
    int e = rowptr[d], e1 = rowptr[d + 1];
    for (; e + 3 < e1; e += 4) {
        int4 s4 = *(const int4*)&csr[e];
        uint4 v0 = A4[s4.x * 16 + l16];
        uint4 v1 = A4[s4.y * 16 + l16];
        uint4 v2 = A4[s4.z * 16 + l16];
        uint4 v3 = A4[s4.w * 16 + l16];
        acc[0] += bf2f(v0.x & 0xFFFFu); acc[1] += bf2f(v0.x >> 16);
        acc[2] += bf2f(v0.y & 0xFFFFu); acc[3] += bf2f(v0.y >> 16);
        acc[4] += bf2f(v0.z & 0xFFFFu); acc[5] += bf2f(v0.z >> 16);
        acc[6] += bf2f(v0.w & 0xFFFFu); acc[7] += bf2f(v0.w >> 16);
        acc[0] += bf2f(v1.x & 0xFFFFu); acc[1] += bf2f(v1.x >> 16);
        acc[2] += bf2f(v1.y & 0xFFFFu); acc[3] += bf2f(v1.y >> 16);
        acc[4] += bf2f(v1.z & 0xFFFFu); acc[5] += bf2f(v1.z >> 16);
        acc[6] += bf2f(v1.w & 0xFFFFu); acc[7] += bf2f(v1.w >> 16);
        acc[0] += bf2f(v2.x & 0xFFFFu); acc[1] += bf2f(v2.x >> 16);
        acc[2] += bf2f(v2.y & 0xFFFFu); acc[3] += bf2f(v2.y >> 16);
        acc[4] += bf2f(v2.z & 0xFFFFu); acc[5] += bf2f(v2.z >> 16);
        acc[6] += bf2f(v2.w & 0xFFFFu); acc[7] += bf2f(v2.w >> 16);
        acc[0] += bf2f(v3.x & 0xFFFFu); acc[1] += bf2f(v3.x >> 16);
        acc[2] += bf2f(v3.y & 0xFFFFu); acc[3] += bf2f(v3.y >> 16);
        acc[4] += bf2f(v3.z & 0xFFFFu); acc[5] += bf2f(v3.z >> 16);
        acc[6] += bf2f(v3.w & 0xFFFFu); acc[7] += bf2f(v3.w >> 16);
    }
    for (; e < e1; ++e) {
        uint4 v = A4[csr[e] * 16 + l16];
        acc[0] += bf2f(v.x & 0xFFFFu); acc[1] += bf2f(v.x >> 16);
        acc[2] += bf2f(v.y & 0xFFFFu); acc[3] += bf2f(v.y >> 16);
        acc[4] += bf2f(v.z & 0xFFFFu); acc[5] += bf2f(v.z >> 16);
        acc[6] += bf2f(v.w & 0xFFFFu); acc[7] += bf2f(v.w >> 16);
    }

    const int c0 = l16 * 8;
    const float di = dinv[d];
    float o[8];
#pragma unroll
    for (int j = 0; j < 8; ++j) {
        int c = c0 + j;
        float sc = gam[c] * rsqrtf(rv[c] + BN_EPS);
        o[j] = fmaxf((acc[j] * di + bs[c] - rm[c]) * sc + bet[c], 0.f);
    }
    if (writeB) {
        uint4 ob;
        ob.x = (unsigned)f2bf(o[0]) | ((unsigned)f2bf(o[1]) << 16);
        ob.y = (unsigned)f2bf(o[2]) | ((unsigned)f2bf(o[3]) << 16);
        ob.z = (unsigned)f2bf(o[4]) | ((unsigned)f2bf(o[5]) << 16);
        ob.w = (unsigned)f2bf(o[6]) | ((unsigned)f2bf(o[7]) << 16);
        ((uint4*)Bb)[d * 16 + l16] = ob;
    }

    __shared__ float4 po[16][32];
    __shared__ int bid[16];
    po[nloc][l16 * 2]     = make_float4(o[0], o[1], o[2], o[3]);
    po[nloc][l16 * 2 + 1] = make_float4(o[4], o[5], o[6], o[7]);
    if (l16 == 0) bid[nloc] = batch[d];
    __syncthreads();
    if (threadIdx.x < 32) {
        int l32 = threadIdx.x;
#pragma unroll
        for (int i = 0; i < 16; ++i) {
            bool lead = true;
            for (int j = 0; j < i; ++j) lead = lead && (bid[j] != bid[i]);
            if (lead) {
                float4 s = po[i][l32];
                for (int j = i + 1; j < 16; ++j)
                    if (bid[j] == bid[i]) add4(s, po[j][l32]);
                float* p = &pooled[bid[i] * FEAT + l32 * 4];
                atomicAdd(p + 0, s.x);
                atomicAdd(p + 1, s.y);
                atomicAdd(p + 2, s.z);
                atomicAdd(p + 3, s.w);
            }
        }
    }
}

// ---- classifier + log_softmax ----
__global__ void k_final(const float* __restrict__ pooled, const int* __restrict__ batch,
        const float* __restrict__ Wc, const float* __restrict__ bc, float* __restrict__ out)
{
    __shared__ float lg[NOUT];
    int g = blockIdx.x;
    int t = threadIdx.x;  // 64
    int start = lbound(batch, NN, g);
    int end = lbound(batch, NN, g + 1);
    float inv = 1.f / fmaxf((float)(end - start), 1.f);
    if (t < NOUT) {
        float acc = bc[t];
        for (int c = 0; c < FEAT; ++c)
            acc = fmaf(pooled[g * FEAT + c] * inv, Wc[c * NOUT + t], acc);
        lg[t] = acc;
    }
    __syncthreads();
    if (t == 0) {
        float m = -1e30f;
        for (int o = 0; o < NOUT; ++o) m = fmaxf(m, lg[o]);
        float ssum = 0.f;
        for (int o = 0; o < NOUT; ++o) ssum += expf(lg[o] - m);
        float lse = m + logf(ssum);
        for (int o = 0; o < NOUT; ++o) out[g * NOUT + o] = lg[o] - lse;
    }
}

extern "C" void kernel_launch(void* const* d_in, const int* in_sizes, int n_in,
                              void* d_out, int out_size, void* d_ws, size_t ws_size,
                              hipStream_t stream)
{
    const float* x      = (const float*)d_in[0];
    const int*   ei     = (const int*)d_in[1];
    const int*   batch  = (const int*)d_in[2];
    const float* Ws     = (const float*)d_in[3];
    const float* bs     = (const float*)d_in[4];
    const float* gammas = (const float*)d_in[5];
    const float* betas  = (const float*)d_in[6];
    const float* rms    = (const float*)d_in[7];
    const float* rvs    = (const float*)d_in[8];
    const float* Wc     = (const float*)d_in[9];
    const float* bc     = (const float*)d_in[10];
    float* out = (float*)d_out;

    float*          dinv   = (float*)d_ws;                     // NN
    float*          pooled = dinv + NN;                        // NG*FEAT
    unsigned short* Bb     = (unsigned short*)(pooled + NG * FEAT);    // NN*HID bf16
    unsigned short* Ab     = Bb + (size_t)NN * HID;            // NN*HID bf16
    unsigned short* xb     = Ab + (size_t)NN * HID;            // NN*HID bf16
    unsigned short* Wt     = xb + (size_t)NN * HID;            // 3*HID*HID bf16
    int*            cnt    = (int*)(Wt + 3 * HID * HID);       // NN
    int*            rowptr = cnt + NN;                         // NN+1
    int*            cursor = rowptr + NN + 1;                  // NN
    int*            bsum   = cursor + NN;                      // NB
    int*            bsumsc = bsum + NB;                        // NB
    int*            csr    = bsumsc + NB;                      // NE

    hipMemsetAsync(cnt, 0, NN * sizeof(int), stream);
    hipMemsetAsync(pooled, 0, NG * FEAT * sizeof(float), stream);

    // CSR build (once; reused for all 3 layers)
    k_count<<<(NE + 255) / 256, 256, 0, stream>>>(ei, cnt);
    k_bsum<<<NB, 256, 0, stream>>>(cnt, bsum);
    k_bscan<<<1, 64, 0, stream>>>(bsum, bsumsc, rowptr);
    k_scan<<<NB, 256, 0, stream>>>(cnt, bsumsc, rowptr, cursor, dinv);
    k_fill<<<(NE / 2 + 255) / 256, 256, 0, stream>>>(ei, cursor, csr, 0, NE / 2);
    k_fill<<<(NE / 2 + 255) / 256, 256, 0, stream>>>(ei, cursor, csr, NE / 2, NE / 2);

    // fused: x->bf16 + x-pool (slice 0) + W transpose
    k_cvtx_pool<<<NN / 16 + 24, 256, 0, stream>>>(x, batch, Ws, xb, Wt, pooled);

    const unsigned short* H = xb;
    for (int L = 0; L < 3; ++L) {
        k_gemm_mfma<<<(NTILE + 3) / 4, 256, 0, stream>>>(H, Wt + L * HID * HID, dinv, Ab);
        k_agg<<<NN / 16, 256, 0, stream>>>(Ab, rowptr, csr, dinv,
            bs + L * HID, gammas + L * HID, betas + L * HID,
            rms + L * HID, rvs + L * HID,
            batch, pooled + (L + 1) * HID, Bb, (L < 2) ? 1 : 0);
        H = Bb;
    }

    k_final<<<NG, 64, 0, stream>>>(pooled, batch, Wc, bc, out);
}

// Round 9
// 305.494 us; speedup vs baseline: 4.2980x; 1.1252x over previous
//
#include <hip/hip_runtime.h>

#define NN 50000
#define NE 800000
#define HID 128
#define NG 128
#define NOUT 10
#define FEAT 512   // 128*3 + 128
#define BN_EPS 1e-5f
#define NB ((NN + 255) / 256)   // 196 scan blocks
#define NTILE (NN / 16)         // 3125 node-tiles

typedef __attribute__((ext_vector_type(8))) short bf16x8;
typedef __attribute__((ext_vector_type(4))) float f32x4;

__device__ __forceinline__ void add4(float4& a, const float4& v) {
    a.x += v.x; a.y += v.y; a.z += v.z; a.w += v.w;
}
__device__ __forceinline__ unsigned short f2bf(float f) {
    unsigned int u = __float_as_uint(f);
    u += 0x7FFFu + ((u >> 16) & 1u);
    return (unsigned short)(u >> 16);
}
__device__ __forceinline__ float bf2f(unsigned int h) {
    return __uint_as_float(h << 16);
}
__device__ __forceinline__ int lbound(const int* __restrict__ b, int n, int v) {
    int lo = 0, hi = n;
    while (lo < hi) { int mid = (lo + hi) >> 1; if (b[mid] < v) lo = mid + 1; else hi = mid; }
    return lo;
}

// ================= CSR build =================
__global__ void k_count(const int* __restrict__ ei, int* __restrict__ cnt) {
    int e = blockIdx.x * 256 + threadIdx.x;
    if (e < NE) atomicAdd(&cnt[ei[NE + e]], 1);
}
__global__ void k_bsum(const int* __restrict__ cnt, int* __restrict__ bsum) {
    __shared__ int sh[256];
    int i = blockIdx.x * 256 + threadIdx.x;
    sh[threadIdx.x] = (i < NN) ? cnt[i] : 0;
    __syncthreads();
    for (int off = 128; off > 0; off >>= 1) {
        if (threadIdx.x < off) sh[threadIdx.x] += sh[threadIdx.x + off];
        __syncthreads();
    }
    if (threadIdx.x == 0) bsum[blockIdx.x] = sh[0];
}
__global__ void k_bscan(const int* __restrict__ bsum, int* __restrict__ bsumsc,
                        int* __restrict__ rowptr) {
    if (threadIdx.x == 0) {
        int run = 0;
        for (int b = 0; b < NB; ++b) { bsumsc[b] = run; run += bsum[b]; }
        rowptr[NN] = NE;
    }
}
__global__ void k_scan(const int* __restrict__ cnt, const int* __restrict__ bsumsc,
                       int* __restrict__ rowptr, int* __restrict__ cursor,
                       float* __restrict__ dinv) {
    __shared__ int sh[256];
    int t = threadIdx.x;
    int i = blockIdx.x * 256 + t;
    int v = (i < NN) ? cnt[i] : 0;
    sh[t] = v;
    __syncthreads();
    for (int off = 1; off < 256; off <<= 1) {
        int add = (t >= off) ? sh[t - off] : 0;
        __syncthreads();
        sh[t] += add;
        __syncthreads();
    }
    if (i < NN) {
        int excl = sh[t] - v + bsumsc[blockIdx.x];
        rowptr[i] = excl;
        cursor[i] = excl;
        dinv[i] = rsqrtf((float)v + 1.0f);   // +1 self-loop
    }
}
__global__ void k_fill(const int* __restrict__ ei, int* __restrict__ cursor,
                       int* __restrict__ csr, int ebase, int ecnt) {
    int e = ebase + blockIdx.x * 256 + threadIdx.x;
    if (e < ebase + ecnt) {
        int pos = atomicAdd(&cursor[ei[NE + e]], 1);
        csr[pos] = ei[e];   // src
    }
}

// ---- W[L][k][c] fp32 -> Wt[L][c][k] bf16 ----
__global__ void k_cvt_w(const float* __restrict__ Ws, unsigned short* __restrict__ Wt) {
    int g0 = blockIdx.x * 2048 + threadIdx.x * 8;
#pragma unroll
    for (int j = 0; j < 8; ++j) {
        int idx = g0 + j;
        int l = idx >> 14, rem = idx & 16383;
        int c = rem >> 7, k = rem & 127;
        Wt[idx] = f2bf(Ws[l * 16384 + k * 128 + c]);
    }
}

// ---- shared device helpers for fused tiles ----
// LDS byte-offset swizzle: row-major [16][128] bf16, XOR row bits into 16B-slot bits.
__device__ __forceinline__ int swz(int row, int col16B) {
    // byte = row*256 + col16B*16, swizzled
    return (row * 256 + col16B * 16) ^ ((row & 7) << 4);
}

// gemm phase: all 4 waves; wave w computes col-tiles ct = 2w, 2w+1.
// sh: swizzled bf16 tile [16][128]; Wt layer slice; out row-block rbase.
__device__ __forceinline__ void tile_gemm(const unsigned short* __restrict__ sh,
        const unsigned short* __restrict__ Wt, const float* __restrict__ dinv,
        unsigned short* __restrict__ Aout, int rbase, int w, int lane)
{
    const int lr = lane & 15;
    const int kg = lane >> 4;
    bf16x8 af[4];
#pragma unroll
    for (int s = 0; s < 4; ++s) {
        int b = (lr * 256 + kg * 16 + s * 64) ^ ((lr & 7) << 4);
        af[s] = *(const bf16x8*)((const char*)sh + b);
    }
    const float4 dv = *(const float4*)&dinv[rbase + kg * 4];
    const float dvj[4] = {dv.x, dv.y, dv.z, dv.w};
#pragma unroll
    for (int cti = 0; cti < 2; ++cti) {
        const int ct = w * 2 + cti;
        const unsigned short* wrow = Wt + (size_t)(ct * 16 + lr) * HID + kg * 8;
        f32x4 acc = {0.f, 0.f, 0.f, 0.f};
#pragma unroll
        for (int s = 0; s < 4; ++s) {
            bf16x8 bf = *(const bf16x8*)(wrow + s * 32);
            acc = __builtin_amdgcn_mfma_f32_16x16x32_bf16(af[s], bf, acc, 0, 0, 0);
        }
#pragma unroll
        for (int j = 0; j < 4; ++j)
            Aout[(size_t)(rbase + kg * 4 + j) * HID + ct * 16 + lr] = f2bf(acc[j] * dvj[j]);
    }
}

// pool combine: first 32 threads; po/bid filled pre-sync.
__device__ __forceinline__ void pool_combine(const float4 (*po)[32], const int* bid,
        float* __restrict__ pooled, int tid)
{
    if (tid < 32) {
#pragma unroll
        for (int i = 0; i < 16; ++i) {
            bool lead = true;
            for (int j = 0; j < i; ++j) lead = lead && (bid[j] != bid[i]);
            if (lead) {
                float4 s = po[i][tid];
                for (int j = i + 1; j < 16; ++j)
                    if (bid[j] == bid[i]) add4(s, po[j][tid]);
                float* p = &pooled[bid[i] * FEAT + tid * 4];
                atomicAdd(p + 0, s.x);
                atomicAdd(p + 1, s.y);
                atomicAdd(p + 2, s.z);
                atomicAdd(p + 3, s.w);
            }
        }
    }
}

// ================= fused: x pool + x->bf16 + gemm W0 -> M =================
__global__ __launch_bounds__(256) void k_x_gemm(const float* __restrict__ x,
        const int* __restrict__ batch, const unsigned short* __restrict__ Wt,
        const float* __restrict__ dinv, float* __restrict__ pooled,
        unsigned short* __restrict__ M)
{
    __shared__ __align__(16) unsigned short sh[16 * 128];
    __shared__ float4 po[16][32];
    __shared__ int bid[16];
    const int t = threadIdx.x;
    const int w = t >> 6;
    const int lane = t & 63;
    const int grp = lane >> 4;
    const int l16 = lane & 15;
    const int nloc = w * 4 + grp;
    const int n = blockIdx.x * 16 + nloc;

    const float4* xr = (const float4*)(x + (size_t)n * HID + l16 * 8);
    float4 a = xr[0], b = xr[1];
    uint4 ob;
    ob.x = (unsigned)f2bf(a.x) | ((unsigned)f2bf(a.y) << 16);
    ob.y = (unsigned)f2bf(a.z) | ((unsigned)f2bf(a.w) << 16);
    ob.z = (unsigned)f2bf(b.x) | ((unsigned)f2bf(b.y) << 16);
    ob.w = (unsigned)f2bf(b.z) | ((unsigned)f2bf(b.w) << 16);
    *(uint4*)((char*)sh + swz(nloc, l16)) = ob;
    po[nloc][l16 * 2]     = a;
    po[nloc][l16 * 2 + 1] = b;
    if (l16 == 0) bid[nloc] = batch[n];
    __syncthreads();

    tile_gemm(sh, Wt, dinv, M, blockIdx.x * 16, w, lane);
    pool_combine(po, bid, pooled, t);
}

// ================= fused: aggregate + BN/ReLU + pool + gemm W_{L+1} -> Mout =================
__global__ __launch_bounds__(256) void k_aggemm(const unsigned short* __restrict__ Ain,
        const int* __restrict__ rowptr, const int* __restrict__ csr,
        const float* __restrict__ dinv, const float* __restrict__ bs,
        const float* __restrict__ gam, const float* __restrict__ bet,
        const float* __restrict__ rm, const float* __restrict__ rv,
        const int* __restrict__ batch, float* __restrict__ pooled,
        const unsigned short* __restrict__ Wt, unsigned short* __restrict__ Mout)
{
    __shared__ __align__(16) unsigned short sh[16 * 128];
    __shared__ float4 po[16][32];
    __shared__ int bid[16];
    const int t = threadIdx.x;
    const int w = t >> 6;
    const int lane = t & 63;
    const int grp = lane >> 4;
    const int l16 = lane & 15;
    const int nloc = w * 4 + grp;
    const int d = blockIdx.x * 16 + nloc;
    const uint4* __restrict__ A4 = (const uint4*)Ain;

    float acc[8];
    {
        uint4 v = A4[d * 16 + l16];          // self-loop term
        acc[0] = bf2f(v.x & 0xFFFFu); acc[1] = bf2f(v.x >> 16);
        acc[2] = bf2f(v.y & 0xFFFFu); acc[3] = bf2f(v.y >> 16);
        acc[4] = bf2f(v.z & 0xFFFFu); acc[5] = bf2f(v.z >> 16);
        acc[6] = bf2f(v.w & 0xFFFFu); acc[7] = bf2f(v.w >> 16);
    }
    int e = rowptr[d], e1 = rowptr[d + 1];
    for (; e + 3 < e1; e += 4) {
        int4 s4 = *(const int4*)&csr[e];
        uint4 v0 = A4[s4.x * 16 + l16];
        uint4 v1 = A4[s4.y * 16 + l16];
        uint4 v2 = A4[s4.z * 16 + l16];
        uint4 v3 = A4[s4.w * 16 + l16];
        acc[0] += bf2f(v0.x & 0xFFFFu); acc[1] += bf2f(v0.x >> 16);
        acc[2] += bf2f(v0.y & 0xFFFFu); acc[3] += bf2f(v0.y >> 16);
        acc[4] += bf2f(v0.z & 0xFFFFu); acc[5] += bf2f(v0.z >> 16);
        acc[6] += bf2f(v0.w & 0xFFFFu); acc[7] += bf2f(v0.w >> 16);
        acc[0] += bf2f(v1.x & 0xFFFFu); acc[1] += bf2f(v1.x >> 16);
        acc[2] += bf2f(v1.y & 0xFFFFu); acc[3] += bf2f(v1.y >> 16);
        acc[4] += bf2f(v1.z & 0xFFFFu); acc[5] += bf2f(v1.z >> 16);
        acc[6] += bf2f(v1.w & 0xFFFFu); acc[7] += bf2f(v1.w >> 16);
        acc[0] += bf2f(v2.x & 0xFFFFu); acc[1] += bf2f(v2.x >> 16);
        acc[2] += bf2f(v2.y & 0xFFFFu); acc[3] += bf2f(v2.y >> 16);
        acc[4] += bf2f(v2.z & 0xFFFFu); acc[5] += bf2f(v2.z >> 16);
        acc[6] += bf2f(v2.w & 0xFFFFu); acc[7] += bf2f(v2.w >> 16);
        acc[0] += bf2f(v3.x & 0xFFFFu); acc[1] += bf2f(v3.x >> 16);
        acc[2] += bf2f(v3.y & 0xFFFFu); acc[3] += bf2f(v3.y >> 16);
        acc[4] += bf2f(v3.z & 0xFFFFu); acc[5] += bf2f(v3.z >> 16);
        acc[6] += bf2f(v3.w & 0xFFFFu); acc[7] += bf2f(v3.w >> 16);
    }
    for (; e < e1; ++e) {
        uint4 v = A4[csr[e] * 16 + l16];
        acc[0] += bf2f(v.x & 0xFFFFu); acc[1] += bf2f(v.x >> 16);
        acc[2] += bf2f(v.y & 0xFFFFu); acc[3] += bf2f(v.y >> 16);
        acc[4] += bf2f(v.z & 0xFFFFu); acc[5] += bf2f(v.z >> 16);
        acc[6] += bf2f(v.w & 0xFFFFu); acc[7] += bf2f(v.w >> 16);
    }

    const int c0 = l16 * 8;
    const float di = dinv[d];
    float o[8];
#pragma unroll
    for (int j = 0; j < 8; ++j) {
        int c = c0 + j;
        float sc = gam[c] * rsqrtf(rv[c] + BN_EPS);
        o[j] = fmaxf((acc[j] * di + bs[c] - rm[c]) * sc + bet[c], 0.f);
    }
    uint4 ob;
    ob.x = (unsigned)f2bf(o[0]) | ((unsigned)f2bf(o[1]) << 16);
    ob.y = (unsigned)f2bf(o[2]) | ((unsigned)f2bf(o[3]) << 16);
    ob.z = (unsigned)f2bf(o[4]) | ((unsigned)f2bf(o[5]) << 16);
    ob.w = (unsigned)f2bf(o[6]) | ((unsigned)f2bf(o[7]) << 16);
    *(uint4*)((char*)sh + swz(nloc, l16)) = ob;
    po[nloc][l16 * 2]     = make_float4(o[0], o[1], o[2], o[3]);
    po[nloc][l16 * 2 + 1] = make_float4(o[4], o[5], o[6], o[7]);
    if (l16 == 0) bid[nloc] = batch[d];
    __syncthreads();

    tile_gemm(sh, Wt, dinv, Mout, blockIdx.x * 16, w, lane);
    pool_combine(po, bid, pooled, t);
}

// ================= last layer: aggregate + BN/ReLU + pool only =================
__global__ __launch_bounds__(256) void k_agg3(const unsigned short* __restrict__ Ain,
        const int* __restrict__ rowptr, const int* __restrict__ csr,
        const float* __restrict__ dinv, const float* __restrict__ bs,
        const float* __restrict__ gam, const float* __restrict__ bet,
        const float* __restrict__ rm, const float* __restrict__ rv,
        const int* __restrict__ batch, float* __restrict__ pooled)
{
    __shared__ float4 po[16][32];
    __shared__ int bid[16];
    const int t = threadIdx.x;
    const int w = t >> 6;
    const int lane = t & 63;
    const int grp = lane >> 4;
    const int l16 = lane & 15;
    const int nloc = w * 4 + grp;
    const int d = blockIdx.x * 16 + nloc;
    const uint4* __restrict__ A4 = (const uint4*)Ain;

    float acc[8];
    {
        uint4 v = A4[d * 16 + l16];
        acc[0] = bf2f(v.x & 0xFFFFu); acc[1] = bf2f(v.x >> 16);
        acc[2] = bf2f(v.y & 0xFFFFu); acc[3] = bf2f(v.y >> 16);
        acc[4] = bf2f(v.z & 0xFFFFu); acc[5] = bf2f(v.z >> 16);
        acc[6] = bf2f(v.w & 0xFFFFu); acc[7] = bf2f(v.w >> 16);
    }
    int e = rowptr[d], e1 = rowptr[d + 1];
    for (; e + 3 < e1; e += 4) {
        int4 s4 = *(const int4*)&csr[e];
        uint4 v0 = A4[s4.x * 16 + l16];
        uint4 v1 = A4[s4.y * 16 + l16];
        uint4 v2 = A4[s4.z * 16 + l16];
        uint4 v3 = A4[s4.w * 16 + l16];
        acc[0] += bf2f(v0.x & 0xFFFFu); acc[1] += bf2f(v0.x >> 16);
        acc[2] += bf2f(v0.y & 0xFFFFu); acc[3] += bf2f(v0.y >> 16);
        acc[4] += bf2f(v0.z & 0xFFFFu); acc[5] += bf2f(v0.z >> 16);
        acc[6] += bf2f(v0.w & 0xFFFFu); acc[7] += bf2f(v0.w >> 16);
        acc[0] += bf2f(v1.x & 0xFFFFu); acc[1] += bf2f(v1.x >> 16);
        acc[2] += bf2f(v1.y & 0xFFFFu); acc[3] += bf2f(v1.y >> 16);
        acc[4] += bf2f(v1.z & 0xFFFFu); acc[5] += bf2f(v1.z >> 16);
        acc[6] += bf2f(v1.w & 0xFFFFu); acc[7] += bf2f(v1.w >> 16);
        acc[0] += bf2f(v2.x & 0xFFFFu); acc[1] += bf2f(v2.x >> 16);
        acc[2] += bf2f(v2.y & 0xFFFFu); acc[3] += bf2f(v2.y >> 16);
        acc[4] += bf2f(v2.z & 0xFFFFu); acc[5] += bf2f(v2.z >> 16);
        acc[6] += bf2f(v2.w & 0xFFFFu); acc[7] += bf2f(v2.w >> 16);
        acc[0] += bf2f(v3.x & 0xFFFFu); acc[1] += bf2f(v3.x >> 16);
        acc[2] += bf2f(v3.y & 0xFFFFu); acc[3] += bf2f(v3.y >> 16);
        acc[4] += bf2f(v3.z & 0xFFFFu); acc[5] += bf2f(v3.z >> 16);
        acc[6] += bf2f(v3.w & 0xFFFFu); acc[7] += bf2f(v3.w >> 16);
    }
    for (; e < e1; ++e) {
        uint4 v = A4[csr[e] * 16 + l16];
        acc[0] += bf2f(v.x & 0xFFFFu); acc[1] += bf2f(v.x >> 16);
        acc[2] += bf2f(v.y & 0xFFFFu); acc[3] += bf2f(v.y >> 16);
        acc[4] += bf2f(v.z & 0xFFFFu); acc[5] += bf2f(v.z >> 16);
        acc[6] += bf2f(v.w & 0xFFFFu); acc[7] += bf2f(v.w >> 16);
    }

    const int c0 = l16 * 8;
    const float di = dinv[d];
    float o[8];
#pragma unroll
    for (int j = 0; j < 8; ++j) {
        int c = c0 + j;
        float sc = gam[c] * rsqrtf(rv[c] + BN_EPS);
        o[j] = fmaxf((acc[j] * di + bs[c] - rm[c]) * sc + bet[c], 0.f);
    }
    po[nloc][l16 * 2]     = make_float4(o[0], o[1], o[2], o[3]);
    po[nloc][l16 * 2 + 1] = make_float4(o[4], o[5], o[6], o[7]);
    if (l16 == 0) bid[nloc] = batch[d];
    __syncthreads();
    pool_combine(po, bid, pooled, t);
}

// ---- classifier + log_softmax ----
__global__ void k_final(const float* __restrict__ pooled, const int* __restrict__ batch,
        const float* __restrict__ Wc, const float* __restrict__ bc, float* __restrict__ out)
{
    __shared__ float lg[NOUT];
    int g = blockIdx.x;
    int t = threadIdx.x;  // 64
    int start = lbound(batch, NN, g);
    int end = lbound(batch, NN, g + 1);
    float inv = 1.f / fmaxf((float)(end - start), 1.f);
    if (t < NOUT) {
        float acc = bc[t];
        for (int c = 0; c < FEAT; ++c)
            acc = fmaf(pooled[g * FEAT + c] * inv, Wc[c * NOUT + t], acc);
        lg[t] = acc;
    }
    __syncthreads();
    if (t == 0) {
        float m = -1e30f;
        for (int o = 0; o < NOUT; ++o) m = fmaxf(m, lg[o]);
        float ssum = 0.f;
        for (int o = 0; o < NOUT; ++o) ssum += expf(lg[o] - m);
        float lse = m + logf(ssum);
        for (int o = 0; o < NOUT; ++o) out[g * NOUT + o] = lg[o] - lse;
    }
}

extern "C" void kernel_launch(void* const* d_in, const int* in_sizes, int n_in,
                              void* d_out, int out_size, void* d_ws, size_t ws_size,
                              hipStream_t stream)
{
    const float* x      = (const float*)d_in[0];
    const int*   ei     = (const int*)d_in[1];
    const int*   batch  = (const int*)d_in[2];
    const float* Ws     = (const float*)d_in[3];
    const float* bs     = (const float*)d_in[4];
    const float* gammas = (const float*)d_in[5];
    const float* betas  = (const float*)d_in[6];
    const float* rms    = (const float*)d_in[7];
    const float* rvs    = (const float*)d_in[8];
    const float* Wc     = (const float*)d_in[9];
    const float* bc     = (const float*)d_in[10];
    float* out = (float*)d_out;

    float*          dinv   = (float*)d_ws;                     // NN
    float*          pooled = dinv + NN;                        // NG*FEAT
    unsigned short* M      = (unsigned short*)(pooled + NG * FEAT);    // NN*HID bf16
    unsigned short* M2     = M + (size_t)NN * HID;             // NN*HID bf16
    unsigned short* Wt     = M2 + (size_t)NN * HID;            // 3*HID*HID bf16
    int*            cnt    = (int*)(Wt + 3 * HID * HID);       // NN
    int*            rowptr = cnt + NN;                         // NN+1
    int*            cursor = rowptr + NN + 1;                  // NN
    int*            bsum   = cursor + NN;                      // NB
    int*            bsumsc = bsum + NB;                        // NB
    int*            csr    = bsumsc + NB;                      // NE

    hipMemsetAsync(cnt, 0, NN * sizeof(int), stream);
    hipMemsetAsync(pooled, 0, NG * FEAT * sizeof(float), stream);

    k_cvt_w<<<24, 256, 0, stream>>>(Ws, Wt);

    // CSR build (once; reused for all 3 layers)
    k_count<<<(NE + 255) / 256, 256, 0, stream>>>(ei, cnt);
    k_bsum<<<NB, 256, 0, stream>>>(cnt, bsum);
    k_bscan<<<1, 64, 0, stream>>>(bsum, bsumsc, rowptr);
    k_scan<<<NB, 256, 0, stream>>>(cnt, bsumsc, rowptr, cursor, dinv);
    k_fill<<<(NE / 2 + 255) / 256, 256, 0, stream>>>(ei, cursor, csr, 0, NE / 2);
    k_fill<<<(NE / 2 + 255) / 256, 256, 0, stream>>>(ei, cursor, csr, NE / 2, NE / 2);

    // layer pipeline (B never materialized)
    k_x_gemm<<<NTILE, 256, 0, stream>>>(x, batch, Wt, dinv, pooled, M);
    k_aggemm<<<NTILE, 256, 0, stream>>>(M, rowptr, csr, dinv,
        bs, gammas, betas, rms, rvs, batch, pooled + 1 * HID,
        Wt + 1 * HID * HID, M2);
    k_aggemm<<<NTILE, 256, 0, stream>>>(M2, rowptr, csr, dinv,
        bs + HID, gammas + HID, betas + HID, rms + HID, rvs + HID,
        batch, pooled + 2 * HID, Wt + 2 * HID * HID, M);
    k_agg3<<<NTILE, 256, 0, stream>>>(M, rowptr, csr, dinv,
        bs + 2 * HID, gammas + 2 * HID, betas + 2 * HID, rms + 2 * HID, rvs + 2 * HID,
        batch, pooled + 3 * HID);

    k_final<<<NG, 64, 0, stream>>>(pooled, batch, Wc, bc, out);
}

// Round 10
// 253.495 us; speedup vs baseline: 5.1797x; 1.2051x over previous
//
#include <hip/hip_runtime.h>

#define NN 50000
#define NE 800000
#define HID 128
#define NG 128
#define NOUT 10
#define FEAT 512   // 128*3 + 128
#define BN_EPS 1e-5f
#define NTILE (NN / 16)         // 3125 node-tiles
#define NBKT 256                // dst>>8 buckets (196 live)
#define NBB  ((NN + 255) / 256) // 196 bucket blocks
#define EPB 4096                // edges per scatter block
#define NSB ((NE + EPB - 1) / EPB) // 196 scatter blocks
#define CAP 8192                // LDS stage capacity (mean bucket 4096)

typedef __attribute__((ext_vector_type(8))) short bf16x8;
typedef __attribute__((ext_vector_type(4))) float f32x4;

__device__ __forceinline__ void add4(float4& a, const float4& v) {
    a.x += v.x; a.y += v.y; a.z += v.z; a.w += v.w;
}
__device__ __forceinline__ unsigned short f2bf(float f) {
    unsigned int u = __float_as_uint(f);
    u += 0x7FFFu + ((u >> 16) & 1u);
    return (unsigned short)(u >> 16);
}
__device__ __forceinline__ float bf2f(unsigned int h) {
    return __uint_as_float(h << 16);
}
__device__ __forceinline__ int lbound(const int* __restrict__ b, int n, int v) {
    int lo = 0, hi = n;
    while (lo < hi) { int mid = (lo + hi) >> 1; if (b[mid] < v) lo = mid + 1; else hi = mid; }
    return lo;
}

// ================= bucketed CSR build =================
__global__ void k_hist(const int* __restrict__ ei, int* __restrict__ bh) {
    __shared__ int h[NBKT];
    h[threadIdx.x] = 0;
    __syncthreads();
    for (int e = blockIdx.x * 256 + threadIdx.x; e < NE; e += gridDim.x * 256)
        atomicAdd(&h[ei[NE + e] >> 8], 1);
    __syncthreads();
    if (h[threadIdx.x]) atomicAdd(&bh[threadIdx.x], h[threadIdx.x]);
}

__global__ void k_hscan(const int* __restrict__ bh, int* __restrict__ bbase,
                        int* __restrict__ bcur) {
    __shared__ int sh[NBKT];
    const int t = threadIdx.x;
    int v = bh[t];
    sh[t] = v;
    __syncthreads();
    for (int off = 1; off < NBKT; off <<= 1) {
        int a = (t >= off) ? sh[t - off] : 0;
        __syncthreads();
        sh[t] += a;
        __syncthreads();
    }
    int excl = sh[t] - v;
    bbase[t] = excl;
    bcur[t] = excl;
    if (t == NBKT - 1) bbase[NBKT] = NE;
}

// bin edges into buckets; per-(block,bucket) contiguous chunk -> coalesced-ish writes
__global__ __launch_bounds__(256) void k_scatter(const int* __restrict__ ei,
        int* __restrict__ bcur, unsigned int* __restrict__ bucketed) {
    __shared__ int bcnt[NBKT];
    __shared__ int gbase[NBKT];
    const int t = threadIdx.x;
    bcnt[t] = 0;
    __syncthreads();
    const int e0 = blockIdx.x * EPB;
#pragma unroll
    for (int i = 0; i < EPB / 256; ++i) {
        int e = e0 + i * 256 + t;
        if (e < NE) atomicAdd(&bcnt[ei[NE + e] >> 8], 1);
    }
    __syncthreads();
    if (bcnt[t]) gbase[t] = atomicAdd(&bcur[t], bcnt[t]);
    __syncthreads();
    bcnt[t] = 0;
    __syncthreads();
#pragma unroll
    for (int i = 0; i < EPB / 256; ++i) {
        int e = e0 + i * 256 + t;
        if (e < NE) {
            int dst = ei[NE + e], src = ei[e];
            int b = dst >> 8;
            int r = atomicAdd(&bcnt[b], 1);
            bucketed[gbase[b] + r] = ((unsigned)(dst & 255) << 16) | (unsigned)src;
        }
    }
}

// per bucket: local count+scan -> rowptr/dinv; stage csr segment in LDS, write coalesced
__global__ __launch_bounds__(256) void k_bucket_csr(const unsigned int* __restrict__ bucketed,
        const int* __restrict__ bbase, unsigned short* __restrict__ csr,
        int* __restrict__ rowptr, float* __restrict__ dinv) {
    __shared__ int cnt[NBKT];
    __shared__ int cur[NBKT];
    __shared__ unsigned short stage[CAP];
    const int b = blockIdx.x;
    const int t = threadIdx.x;
    const int lo = bbase[b], hi = bbase[b + 1], n = hi - lo;
    cnt[t] = 0;
    __syncthreads();
    for (int i = t; i < n; i += 256) atomicAdd(&cnt[bucketed[lo + i] >> 16], 1);
    __syncthreads();
    int v = cnt[t];
    cur[t] = v;
    __syncthreads();
    for (int off = 1; off < NBKT; off <<= 1) {
        int a = (t >= off) ? cur[t - off] : 0;
        __syncthreads();
        cur[t] += a;
        __syncthreads();
    }
    int excl = cur[t] - v;
    int d = b * 256 + t;
    if (d < NN) {
        rowptr[d] = lo + excl;
        dinv[d] = rsqrtf((float)v + 1.0f);   // +1 self-loop
    }
    if (d == NN) rowptr[NN] = NE;
    __syncthreads();
    cur[t] = excl;
    __syncthreads();
    if (n <= CAP) {
        for (int i = t; i < n; i += 256) {
            unsigned p = bucketed[lo + i];
            int r = atomicAdd(&cur[p >> 16], 1);
            stage[r] = (unsigned short)(p & 0xFFFFu);
        }
        __syncthreads();
        for (int i = t; i < n; i += 256) csr[lo + i] = stage[i];
    } else {  // paranoia fallback (never taken for this input)
        for (int i = t; i < n; i += 256) {
            unsigned p = bucketed[lo + i];
            int r = atomicAdd(&cur[p >> 16], 1);
            csr[lo + r] = (unsigned short)(p & 0xFFFFu);
        }
    }
}

// ---- W[L][k][c] fp32 -> Wt[L][c][k] bf16 ----
__global__ void k_cvt_w(const float* __restrict__ Ws, unsigned short* __restrict__ Wt) {
    int g0 = blockIdx.x * 2048 + threadIdx.x * 8;
#pragma unroll
    for (int j = 0; j < 8; ++j) {
        int idx = g0 + j;
        int l = idx >> 14, rem = idx & 16383;
        int c = rem >> 7, k = rem & 127;
        Wt[idx] = f2bf(Ws[l * 16384 + k * 128 + c]);
    }
}

// ---- shared device helpers for fused tiles ----
__device__ __forceinline__ int swz(int row, int col16B) {
    return (row * 256 + col16B * 16) ^ ((row & 7) << 4);
}

__device__ __forceinline__ void tile_gemm(const unsigned short* __restrict__ sh,
        const unsigned short* __restrict__ Wt, const float* __restrict__ dinv,
        unsigned short* __restrict__ Aout, int rbase, int w, int lane)
{
    const int lr = lane & 15;
    const int kg = lane >> 4;
    bf16x8 af[4];
#pragma unroll
    for (int s = 0; s < 4; ++s) {
        int b = (lr * 256 + kg * 16 + s * 64) ^ ((lr & 7) << 4);
        af[s] = *(const bf16x8*)((const char*)sh + b);
    }
    const float4 dv = *(const float4*)&dinv[rbase + kg * 4];
    const float dvj[4] = {dv.x, dv.y, dv.z, dv.w};
#pragma unroll
    for (int cti = 0; cti < 2; ++cti) {
        const int ct = w * 2 + cti;
        const unsigned short* wrow = Wt + (size_t)(ct * 16 + lr) * HID + kg * 8;
        f32x4 acc = {0.f, 0.f, 0.f, 0.f};
#pragma unroll
        for (int s = 0; s < 4; ++s) {
            bf16x8 bf = *(const bf16x8*)(wrow + s * 32);
            acc = __builtin_amdgcn_mfma_f32_16x16x32_bf16(af[s], bf, acc, 0, 0, 0);
        }
#pragma unroll
        for (int j = 0; j < 4; ++j)
            Aout[(size_t)(rbase + kg * 4 + j) * HID + ct * 16 + lr] = f2bf(acc[j] * dvj[j]);
    }
}

__device__ __forceinline__ void pool_combine(const float4 (*po)[32], const int* bid,
        float* __restrict__ pooled, int tid)
{
    if (tid < 32) {
#pragma unroll
        for (int i = 0; i < 16; ++i) {
            bool lead = true;
            for (int j = 0; j < i; ++j) lead = lead && (bid[j] != bid[i]);
            if (lead) {
                float4 s = po[i][tid];
                for (int j = i + 1; j < 16; ++j)
                    if (bid[j] == bid[i]) add4(s, po[j][tid]);
                float* p = &pooled[bid[i] * FEAT + tid * 4];
                atomicAdd(p + 0, s.x);
                atomicAdd(p + 1, s.y);
                atomicAdd(p + 2, s.z);
                atomicAdd(p + 3, s.w);
            }
        }
    }
}

// ================= fused: x pool + x->bf16 + gemm W0 -> M =================
__global__ __launch_bounds__(256) void k_x_gemm(const float* __restrict__ x,
        const int* __restrict__ batch, const unsigned short* __restrict__ Wt,
        const float* __restrict__ dinv, float* __restrict__ pooled,
        unsigned short* __restrict__ M)
{
    __shared__ __align__(16) unsigned short sh[16 * 128];
    __shared__ float4 po[16][32];
    __shared__ int bid[16];
    const int t = threadIdx.x;
    const int w = t >> 6;
    const int lane = t & 63;
    const int grp = lane >> 4;
    const int l16 = lane & 15;
    const int nloc = w * 4 + grp;
    const int n = blockIdx.x * 16 + nloc;

    const float4* xr = (const float4*)(x + (size_t)n * HID + l16 * 8);
    float4 a = xr[0], b = xr[1];
    uint4 ob;
    ob.x = (unsigned)f2bf(a.x) | ((unsigned)f2bf(a.y) << 16);
    ob.y = (unsigned)f2bf(a.z) | ((unsigned)f2bf(a.w) << 16);
    ob.z = (unsigned)f2bf(b.x) | ((unsigned)f2bf(b.y) << 16);
    ob.w = (unsigned)f2bf(b.z) | ((unsigned)f2bf(b.w) << 16);
    *(uint4*)((char*)sh + swz(nloc, l16)) = ob;
    po[nloc][l16 * 2]     = a;
    po[nloc][l16 * 2 + 1] = b;
    if (l16 == 0) bid[nloc] = batch[n];
    __syncthreads();

    tile_gemm(sh, Wt, dinv, M, blockIdx.x * 16, w, lane);
    pool_combine(po, bid, pooled, t);
}

// ================= fused: aggregate + BN/ReLU + pool + gemm W_{L+1} -> Mout =================
__global__ __launch_bounds__(256) void k_aggemm(const unsigned short* __restrict__ Ain,
        const int* __restrict__ rowptr, const unsigned short* __restrict__ csr,
        const float* __restrict__ dinv, const float* __restrict__ bs,
        const float* __restrict__ gam, const float* __restrict__ bet,
        const float* __restrict__ rm, const float* __restrict__ rv,
        const int* __restrict__ batch, float* __restrict__ pooled,
        const unsigned short* __restrict__ Wt, unsigned short* __restrict__ Mout)
{
    __shared__ __align__(16) unsigned short sh[16 * 128];
    __shared__ float4 po[16][32];
    __shared__ int bid[16];
    const int t = threadIdx.x;
    const int w = t >> 6;
    const int lane = t & 63;
    const int grp = lane >> 4;
    const int l16 = lane & 15;
    const int nloc = w * 4 + grp;
    const int d = blockIdx.x * 16 + nloc;
    const uint4* __restrict__ A4 = (const uint4*)Ain;

    float acc[8];
    {
        uint4 v = A4[d * 16 + l16];          // self-loop term
        acc[0] = bf2f(v.x & 0xFFFFu); acc[1] = bf2f(v.x >> 16);
        acc[2] = bf2f(v.y & 0xFFFFu); acc[3] = bf2f(v.y >> 16);
        acc[4] = bf2f(v.z & 0xFFFFu); acc[5] = bf2f(v.z >> 16);
        acc[6] = bf2f(v.w & 0xFFFFu); acc[7] = bf2f(v.w >> 16);
    }
    int e = rowptr[d], e1 = rowptr[d + 1];
    for (; e + 3 < e1; e += 4) {
        int s0 = csr[e], s1 = csr[e + 1], s2 = csr[e + 2], s3 = csr[e + 3];
        uint4 v0 = A4[s0 * 16 + l16];
        uint4 v1 = A4[s1 * 16 + l16];
        uint4 v2 = A4[s2 * 16 + l16];
        uint4 v3 = A4[s3 * 16 + l16];
        acc[0] += bf2f(v0.x & 0xFFFFu); acc[1] += bf2f(v0.x >> 16);
        acc[2] += bf2f(v0.y & 0xFFFFu); acc[3] += bf2f(v0.y >> 16);
        acc[4] += bf2f(v0.z & 0xFFFFu); acc[5] += bf2f(v0.z >> 16);
        acc[6] += bf2f(v0.w & 0xFFFFu); acc[7] += bf2f(v0.w >> 16);
        acc[0] += bf2f(v1.x & 0xFFFFu); acc[1] += bf2f(v1.x >> 16);
        acc[2] += bf2f(v1.y & 0xFFFFu); acc[3] += bf2f(v1.y >> 16);
        acc[4] += bf2f(v1.z & 0xFFFFu); acc[5] += bf2f(v1.z >> 16);
        acc[6] += bf2f(v1.w & 0xFFFFu); acc[7] += bf2f(v1.w >> 16);
        acc[0] += bf2f(v2.x & 0xFFFFu); acc[1] += bf2f(v2.x >> 16);
        acc[2] += bf2f(v2.y & 0xFFFFu); acc[3] += bf2f(v2.y >> 16);
        acc[4] += bf2f(v2.z & 0xFFFFu); acc[5] += bf2f(v2.z >> 16);
        acc[6] += bf2f(v2.w & 0xFFFFu); acc[7] += bf2f(v2.w >> 16);
        acc[0] += bf2f(v3.x & 0xFFFFu); acc[1] += bf2f(v3.x >> 16);
        acc[2] += bf2f(v3.y & 0xFFFFu); acc[3] += bf2f(v3.y >> 16);
        acc[4] += bf2f(v3.z & 0xFFFFu); acc[5] += bf2f(v3.z >> 16);
        acc[6] += bf2f(v3.w & 0xFFFFu); acc[7] += bf2f(v3.w >> 16);
    }
    for (; e < e1; ++e) {
        uint4 v = A4[csr[e] * 16 + l16];
        acc[0] += bf2f(v.x & 0xFFFFu); acc[1] += bf2f(v.x >> 16);
        acc[2] += bf2f(v.y & 0xFFFFu); acc[3] += bf2f(v.y >> 16);
        acc[4] += bf2f(v.z & 0xFFFFu); acc[5] += bf2f(v.z >> 16);
        acc[6] += bf2f(v.w & 0xFFFFu); acc[7] += bf2f(v.w >> 16);
    }

    const int c0 = l16 * 8;
    const float di = dinv[d];
    float o[8];
#pragma unroll
    for (int j = 0; j < 8; ++j) {
        int c = c0 + j;
        float sc = gam[c] * rsqrtf(rv[c] + BN_EPS);
        o[j] = fmaxf((acc[j] * di + bs[c] - rm[c]) * sc + bet[c], 0.f);
    }
    uint4 ob;
    ob.x = (unsigned)f2bf(o[0]) | ((unsigned)f2bf(o[1]) << 16);
    ob.y = (unsigned)f2bf(o[2]) | ((unsigned)f2bf(o[3]) << 16);
    ob.z = (unsigned)f2bf(o[4]) | ((unsigned)f2bf(o[5]) << 16);
    ob.w = (unsigned)f2bf(o[6]) | ((unsigned)f2bf(o[7]) << 16);
    *(uint4*)((char*)sh + swz(nloc, l16)) = ob;
    po[nloc][l16 * 2]     = make_float4(o[0], o[1], o[2], o[3]);
    po[nloc][l16 * 2 + 1] = make_float4(o[4], o[5], o[6], o[7]);
    if (l16 == 0) bid[nloc] = batch[d];
    __syncthreads();

    tile_gemm(sh, Wt, dinv, Mout, blockIdx.x * 16, w, lane);
    pool_combine(po, bid, pooled, t);
}

// ================= last layer: aggregate + BN/ReLU + pool only =================
__global__ __launch_bounds__(256) void k_agg3(const unsigned short* __restrict__ Ain,
        const int* __restrict__ rowptr, const unsigned short* __restrict__ csr,
        const float* __restrict__ dinv, const float* __restrict__ bs,
        const float* __restrict__ gam, const float* __restrict__ bet,
        const float* __restrict__ rm, const float* __restrict__ rv,
        const int* __restrict__ batch, float* __restrict__ pooled)
{
    __shared__ float4 po[16][32];
    __shared__ int bid[16];
    const int t = threadIdx.x;
    const int w = t >> 6;
    const int lane = t & 63;
    const int grp = lane >> 4;
    const int l16 = lane & 15;
    const int nloc = w * 4 + grp;
    const int d = blockIdx.x * 16 + nloc;
    const uint4* __restrict__ A4 = (const uint4*)Ain;

    float acc[8];
    {
        uint4 v = A4[d * 16 + l16];
        acc[0] = bf2f(v.x & 0xFFFFu); acc[1] = bf2f(v.x >> 16);
        acc[2] = bf2f(v.y & 0xFFFFu); acc[3] = bf2f(v.y >> 16);
        acc[4] = bf2f(v.z & 0xFFFFu); acc[5] = bf2f(v.z >> 16);
        acc[6] = bf2f(v.w & 0xFFFFu); acc[7] = bf2f(v.w >> 16);
    }
    int e = rowptr[d], e1 = rowptr[d + 1];
    for (; e + 3 < e1; e += 4) {
        int s0 = csr[e], s1 = csr[e + 1], s2 = csr[e + 2], s3 = csr[e + 3];
        uint4 v0 = A4[s0 * 16 + l16];
        uint4 v1 = A4[s1 * 16 + l16];
        uint4 v2 = A4[s2 * 16 + l16];
        uint4 v3 = A4[s3 * 16 + l16];
        acc[0] += bf2f(v0.x & 0xFFFFu); acc[1] += bf2f(v0.x >> 16);
        acc[2] += bf2f(v0.y & 0xFFFFu); acc[3] += bf2f(v0.y >> 16);
        acc[4] += bf2f(v0.z & 0xFFFFu); acc[5] += bf2f(v0.z >> 16);
        acc[6] += bf2f(v0.w & 0xFFFFu); acc[7] += bf2f(v0.w >> 16);
        acc[0] += bf2f(v1.x & 0xFFFFu); acc[1] += bf2f(v1.x >> 16);
        acc[2] += bf2f(v1.y & 0xFFFFu); acc[3] += bf2f(v1.y >> 16);
        acc[4] += bf2f(v1.z & 0xFFFFu); acc[5] += bf2f(v1.z >> 16);
        acc[6] += bf2f(v1.w & 0xFFFFu); acc[7] += bf2f(v1.w >> 16);
        acc[0] += bf2f(v2.x & 0xFFFFu); acc[1] += bf2f(v2.x >> 16);
        acc[2] += bf2f(v2.y & 0xFFFFu); acc[3] += bf2f(v2.y >> 16);
        acc[4] += bf2f(v2.z & 0xFFFFu); acc[5] += bf2f(v2.z >> 16);
        acc[6] += bf2f(v2.w & 0xFFFFu); acc[7] += bf2f(v2.w >> 16);
        acc[0] += bf2f(v3.x & 0xFFFFu); acc[1] += bf2f(v3.x >> 16);
        acc[2] += bf2f(v3.y & 0xFFFFu); acc[3] += bf2f(v3.y >> 16);
        acc[4] += bf2f(v3.z & 0xFFFFu); acc[5] += bf2f(v3.z >> 16);
        acc[6] += bf2f(v3.w & 0xFFFFu); acc[7] += bf2f(v3.w >> 16);
    }
    for (; e < e1; ++e) {
        uint4 v = A4[csr[e] * 16 + l16];
        acc[0] += bf2f(v.x & 0xFFFFu); acc[1] += bf2f(v.x >> 16);
        acc[2] += bf2f(v.y & 0xFFFFu); acc[3] += bf2f(v.y >> 16);
        acc[4] += bf2f(v.z & 0xFFFFu); acc[5] += bf2f(v.z >> 16);
        acc[6] += bf2f(v.w & 0xFFFFu); acc[7] += bf2f(v.w >> 16);
    }

    const int c0 = l16 * 8;
    const float di = dinv[d];
    float o[8];
#pragma unroll
    for (int j = 0; j < 8; ++j) {
        int c = c0 + j;
        float sc = gam[c] * rsqrtf(rv[c] + BN_EPS);
        o[j] = fmaxf((acc[j] * di + bs[c] - rm[c]) * sc + bet[c], 0.f);
    }
    po[nloc][l16 * 2]     = make_float4(o[0], o[1], o[2], o[3]);
    po[nloc][l16 * 2 + 1] = make_float4(o[4], o[5], o[6], o[7]);
    if (l16 == 0) bid[nloc] = batch[d];
    __syncthreads();
    pool_combine(po, bid, pooled, t);
}

// ---- classifier + log_softmax ----
__global__ void k_final(const float* __restrict__ pooled, const int* __restrict__ batch,
        const float* __restrict__ Wc, const float* __restrict__ bc, float* __restrict__ out)
{
    __shared__ float lg[NOUT];
    int g = blockIdx.x;
    int t = threadIdx.x;  // 64
    int start = lbound(batch, NN, g);
    int end = lbound(batch, NN, g + 1);
    float inv = 1.f / fmaxf((float)(end - start), 1.f);
    if (t < NOUT) {
        float acc = bc[t];
        for (int c = 0; c < FEAT; ++c)
            acc = fmaf(pooled[g * FEAT + c] * inv, Wc[c * NOUT + t], acc);
        lg[t] = acc;
    }
    __syncthreads();
    if (t == 0) {
        float m = -1e30f;
        for (int o = 0; o < NOUT; ++o) m = fmaxf(m, lg[o]);
        float ssum = 0.f;
        for (int o = 0; o < NOUT; ++o) ssum += expf(lg[o] - m);
        float lse = m + logf(ssum);
        for (int o = 0; o < NOUT; ++o) out[g * NOUT + o] = lg[o] - lse;
    }
}

extern "C" void kernel_launch(void* const* d_in, const int* in_sizes, int n_in,
                              void* d_out, int out_size, void* d_ws, size_t ws_size,
                              hipStream_t stream)
{
    const float* x      = (const float*)d_in[0];
    const int*   ei     = (const int*)d_in[1];
    const int*   batch  = (const int*)d_in[2];
    const float* Ws     = (const float*)d_in[3];
    const float* bs     = (const float*)d_in[4];
    const float* gammas = (const float*)d_in[5];
    const float* betas  = (const float*)d_in[6];
    const float* rms    = (const float*)d_in[7];
    const float* rvs    = (const float*)d_in[8];
    const float* Wc     = (const float*)d_in[9];
    const float* bc     = (const float*)d_in[10];
    float* out = (float*)d_out;

    float*          dinv     = (float*)d_ws;                   // NN
    float*          pooled   = dinv + NN;                      // NG*FEAT
    unsigned short* M        = (unsigned short*)(pooled + NG * FEAT);  // NN*HID bf16
    unsigned short* M2       = M + (size_t)NN * HID;           // NN*HID bf16
    unsigned short* Wt       = M2 + (size_t)NN * HID;          // 3*HID*HID bf16
    int*            rowptr   = (int*)(Wt + 3 * HID * HID);     // NN+1
    int*            bh       = rowptr + NN + 1;                // NBKT
    int*            bbase    = bh + NBKT;                      // NBKT+1
    int*            bcur     = bbase + NBKT + 1;               // NBKT
    unsigned int*   bucketed = (unsigned int*)(bcur + NBKT);   // NE
    unsigned short* csr      = (unsigned short*)(bucketed + NE); // NE ushort

    hipMemsetAsync(bh, 0, NBKT * sizeof(int), stream);
    hipMemsetAsync(pooled, 0, NG * FEAT * sizeof(float), stream);

    k_cvt_w<<<24, 256, 0, stream>>>(Ws, Wt);

    // bucketed CSR build (once; reused for all 3 layers)
    k_hist<<<128, 256, 0, stream>>>(ei, bh);
    k_hscan<<<1, NBKT, 0, stream>>>(bh, bbase, bcur);
    k_scatter<<<NSB, 256, 0, stream>>>(ei, bcur, bucketed);
    k_bucket_csr<<<NBB, 256, 0, stream>>>(bucketed, bbase, csr, rowptr, dinv);

    // layer pipeline (B never materialized)
    k_x_gemm<<<NTILE, 256, 0, stream>>>(x, batch, Wt, dinv, pooled, M);
    k_aggemm<<<NTILE, 256, 0, stream>>>(M, rowptr, csr, dinv,
        bs, gammas, betas, rms, rvs, batch, pooled + 1 * HID,
        Wt + 1 * HID * HID, M2);
    k_aggemm<<<NTILE, 256, 0, stream>>>(M2, rowptr, csr, dinv,
        bs + HID, gammas + HID, betas + HID, rms + HID, rvs + HID,
        batch, pooled + 2 * HID, Wt + 2 * HID * HID, M);
    k_agg3<<<NTILE, 256, 0, stream>>>(M, rowptr, csr, dinv,
        bs + 2 * HID, gammas + 2 * HID, betas + 2 * HID, rms + 2 * HID, rvs + 2 * HID,
        batch, pooled + 3 * HID);

    k_final<<<NG, 64, 0, stream>>>(pooled, batch, Wc, bc, out);
}

// Round 11
// 237.296 us; speedup vs baseline: 5.5333x; 1.0683x over previous
//
#include <hip/hip_runtime.h>

#define NN 50000
#define NE 800000
#define HID 128
#define NG 128
#define NOUT 10
#define FEAT 512   // 128*3 + 128
#define BN_EPS 1e-5f
#define NTILE (NN / 16)         // 3125 node-tiles
#define NBKT 256                // dst>>8 buckets (196 live)
#define NBB  ((NN + 255) / 256) // 196 bucket blocks
#define EPB 4096                // edges per scatter block
#define NSB ((NE + EPB - 1) / EPB) // 196 scatter blocks
#define CAPB 6144               // fixed per-bucket region (mean 4096, +32 sigma)
#define CAP 8192                // LDS stage capacity

typedef __attribute__((ext_vector_type(8))) short bf16x8;
typedef __attribute__((ext_vector_type(4))) float f32x4;

__device__ __forceinline__ void add4(float4& a, const float4& v) {
    a.x += v.x; a.y += v.y; a.z += v.z; a.w += v.w;
}
__device__ __forceinline__ unsigned short f2bf(float f) {
    unsigned int u = __float_as_uint(f);
    u += 0x7FFFu + ((u >> 16) & 1u);
    return (unsigned short)(u >> 16);
}
__device__ __forceinline__ float bf2f(unsigned int h) {
    return __uint_as_float(h << 16);
}
__device__ __forceinline__ int lbound(const int* __restrict__ b, int n, int v) {
    int lo = 0, hi = n;
    while (lo < hi) { int mid = (lo + hi) >> 1; if (b[mid] < v) lo = mid + 1; else hi = mid; }
    return lo;
}

// ================= prep: W transpose->bf16, zero bh, zero pooled =================
__global__ __launch_bounds__(256) void k_prep(const float* __restrict__ Ws,
        unsigned short* __restrict__ Wt, int* __restrict__ bh, float* __restrict__ pooled)
{
    const int b = blockIdx.x;
    if (b < 24) {
        int g0 = b * 2048 + threadIdx.x * 8;
#pragma unroll
        for (int j = 0; j < 8; ++j) {
            int idx = g0 + j;
            int l = idx >> 14, rem = idx & 16383;
            int c = rem >> 7, k = rem & 127;
            Wt[idx] = f2bf(Ws[l * 16384 + k * 128 + c]);
        }
    } else if (b == 24) {
        bh[threadIdx.x] = 0;
    } else {
        // blocks 25,26: zero pooled (NG*FEAT = 65536 floats = 16384 float4)
        float4* p = (float4*)pooled;
        int i0 = (b - 25) * 8192 + threadIdx.x;
        for (int i = i0; i < (b - 25) * 8192 + 8192; i += 256)
            p[i] = make_float4(0.f, 0.f, 0.f, 0.f);
    }
}

// ================= bucketed CSR build =================
__global__ __launch_bounds__(256) void k_scatter(const int* __restrict__ ei,
        int* __restrict__ bh, unsigned int* __restrict__ bucketed) {
    __shared__ int bcnt[NBKT];
    __shared__ int gbase[NBKT];
    const int t = threadIdx.x;
    bcnt[t] = 0;
    __syncthreads();
    const int e0 = blockIdx.x * EPB;
#pragma unroll
    for (int i = 0; i < EPB / 256; ++i) {
        int e = e0 + i * 256 + t;
        if (e < NE) atomicAdd(&bcnt[ei[NE + e] >> 8], 1);
    }
    __syncthreads();
    if (bcnt[t]) gbase[t] = atomicAdd(&bh[t], bcnt[t]);
    __syncthreads();
    bcnt[t] = 0;
    __syncthreads();
#pragma unroll
    for (int i = 0; i < EPB / 256; ++i) {
        int e = e0 + i * 256 + t;
        if (e < NE) {
            int dst = ei[NE + e], src = ei[e];
            int bkt = dst >> 8;
            int r = atomicAdd(&bcnt[bkt], 1);
            bucketed[bkt * CAPB + gbase[bkt] + r] = ((unsigned)(dst & 255) << 16) | (unsigned)src;
        }
    }
}

__global__ void k_hscan(const int* __restrict__ bh, int* __restrict__ bbase) {
    __shared__ int sh[NBKT];
    const int t = threadIdx.x;
    int v = bh[t];
    sh[t] = v;
    __syncthreads();
    for (int off = 1; off < NBKT; off <<= 1) {
        int a = (t >= off) ? sh[t - off] : 0;
        __syncthreads();
        sh[t] += a;
        __syncthreads();
    }
    bbase[t] = sh[t] - v;
    if (t == NBKT - 1) bbase[NBKT] = sh[t];
}

__global__ __launch_bounds__(256) void k_bucket_csr(const unsigned int* __restrict__ bucketed,
        const int* __restrict__ bh, const int* __restrict__ bbase,
        unsigned short* __restrict__ csr, int* __restrict__ rowptr, float* __restrict__ dinv) {
    __shared__ int cnt[NBKT];
    __shared__ int cur[NBKT];
    __shared__ unsigned short stage[CAP];
    const int b = blockIdx.x;
    const int t = threadIdx.x;
    const int n = bh[b];
    const int rbase = b * CAPB;      // read base (fixed region)
    const int wbase = bbase[b];      // write base (dense csr)
    cnt[t] = 0;
    __syncthreads();
    for (int i = t; i < n; i += 256) atomicAdd(&cnt[bucketed[rbase + i] >> 16], 1);
    __syncthreads();
    int v = cnt[t];
    cur[t] = v;
    __syncthreads();
    for (int off = 1; off < NBKT; off <<= 1) {
        int a = (t >= off) ? cur[t - off] : 0;
        __syncthreads();
        cur[t] += a;
        __syncthreads();
    }
    int excl = cur[t] - v;
    int d = b * 256 + t;
    if (d < NN) {
        rowptr[d] = wbase + excl;
        dinv[d] = rsqrtf((float)v + 1.0f);   // +1 self-loop
    }
    if (d == NN) rowptr[NN] = NE;
    __syncthreads();
    cur[t] = excl;
    __syncthreads();
    if (n <= CAP) {
        for (int i = t; i < n; i += 256) {
            unsigned p = bucketed[rbase + i];
            int r = atomicAdd(&cur[p >> 16], 1);
            stage[r] = (unsigned short)(p & 0xFFFFu);
        }
        __syncthreads();
        for (int i = t; i < n; i += 256) csr[wbase + i] = stage[i];
    } else {  // paranoia fallback (never taken for this input)
        for (int i = t; i < n; i += 256) {
            unsigned p = bucketed[rbase + i];
            int r = atomicAdd(&cur[p >> 16], 1);
            csr[wbase + r] = (unsigned short)(p & 0xFFFFu);
        }
    }
}

// ---- shared device helpers ----
__device__ __forceinline__ int swz(int row, int col16B) {
    return (row * 256 + col16B * 16) ^ ((row & 7) << 4);
}

__device__ __forceinline__ void accinit(float* a, uint4 v) {
    a[0] = bf2f(v.x & 0xFFFFu); a[1] = bf2f(v.x >> 16);
    a[2] = bf2f(v.y & 0xFFFFu); a[3] = bf2f(v.y >> 16);
    a[4] = bf2f(v.z & 0xFFFFu); a[5] = bf2f(v.z >> 16);
    a[6] = bf2f(v.w & 0xFFFFu); a[7] = bf2f(v.w >> 16);
}
__device__ __forceinline__ void acc8(float* a, uint4 v) {
    a[0] += bf2f(v.x & 0xFFFFu); a[1] += bf2f(v.x >> 16);
    a[2] += bf2f(v.y & 0xFFFFu); a[3] += bf2f(v.y >> 16);
    a[4] += bf2f(v.z & 0xFFFFu); a[5] += bf2f(v.z >> 16);
    a[6] += bf2f(v.w & 0xFFFFu); a[7] += bf2f(v.w >> 16);
}

// 8-deep unrolled row gather; per-channel accumulation order preserved
__device__ __forceinline__ void gather_rows(const uint4* __restrict__ A4,
        const unsigned short* __restrict__ csr, int e, int e1, int l16, float* acc)
{
    for (; e + 7 < e1; e += 8) {
        int s0 = csr[e],     s1 = csr[e + 1], s2 = csr[e + 2], s3 = csr[e + 3];
        int s4 = csr[e + 4], s5 = csr[e + 5], s6 = csr[e + 6], s7 = csr[e + 7];
        uint4 v0 = A4[s0 * 16 + l16];
        uint4 v1 = A4[s1 * 16 + l16];
        uint4 v2 = A4[s2 * 16 + l16];
        uint4 v3 = A4[s3 * 16 + l16];
        uint4 v4 = A4[s4 * 16 + l16];
        uint4 v5 = A4[s5 * 16 + l16];
        uint4 v6 = A4[s6 * 16 + l16];
        uint4 v7 = A4[s7 * 16 + l16];
        acc8(acc, v0); acc8(acc, v1); acc8(acc, v2); acc8(acc, v3);
        acc8(acc, v4); acc8(acc, v5); acc8(acc, v6); acc8(acc, v7);
    }
    for (; e + 3 < e1; e += 4) {
        int s0 = csr[e], s1 = csr[e + 1], s2 = csr[e + 2], s3 = csr[e + 3];
        uint4 v0 = A4[s0 * 16 + l16];
        uint4 v1 = A4[s1 * 16 + l16];
        uint4 v2 = A4[s2 * 16 + l16];
        uint4 v3 = A4[s3 * 16 + l16];
        acc8(acc, v0); acc8(acc, v1); acc8(acc, v2); acc8(acc, v3);
    }
    for (; e < e1; ++e) acc8(acc, A4[csr[e] * 16 + l16]);
}

__device__ __forceinline__ void bn_relu(const float* acc, float di, int c0,
        const float* __restrict__ bs, const float* __restrict__ gam,
        const float* __restrict__ bet, const float* __restrict__ rm,
        const float* __restrict__ rv, float* o)
{
    float4 g0 = *(const float4*)&gam[c0], g1 = *(const float4*)&gam[c0 + 4];
    float4 r0 = *(const float4*)&rv[c0],  r1 = *(const float4*)&rv[c0 + 4];
    float4 b0 = *(const float4*)&bs[c0],  b1 = *(const float4*)&bs[c0 + 4];
    float4 m0 = *(const float4*)&rm[c0],  m1 = *(const float4*)&rm[c0 + 4];
    float4 e0 = *(const float4*)&bet[c0], e1v = *(const float4*)&bet[c0 + 4];
    float gg[8] = {g0.x, g0.y, g0.z, g0.w, g1.x, g1.y, g1.z, g1.w};
    float rr[8] = {r0.x, r0.y, r0.z, r0.w, r1.x, r1.y, r1.z, r1.w};
    float bb[8] = {b0.x, b0.y, b0.z, b0.w, b1.x, b1.y, b1.z, b1.w};
    float mm[8] = {m0.x, m0.y, m0.z, m0.w, m1.x, m1.y, m1.z, m1.w};
    float ee[8] = {e0.x, e0.y, e0.z, e0.w, e1v.x, e1v.y, e1v.z, e1v.w};
#pragma unroll
    for (int j = 0; j < 8; ++j) {
        float sc = gg[j] * rsqrtf(rr[j] + BN_EPS);
        o[j] = fmaxf((acc[j] * di + bb[j] - mm[j]) * sc + ee[j], 0.f);
    }
}

__device__ __forceinline__ void tile_gemm(const unsigned short* __restrict__ sh,
        const unsigned short* __restrict__ Wt, const float* __restrict__ dinv,
        unsigned short* __restrict__ Aout, int rbase, int w, int lane)
{
    const int lr = lane & 15;
    const int kg = lane >> 4;
    bf16x8 af[4];
#pragma unroll
    for (int s = 0; s < 4; ++s) {
        int b = (lr * 256 + kg * 16 + s * 64) ^ ((lr & 7) << 4);
        af[s] = *(const bf16x8*)((const char*)sh + b);
    }
    const float4 dv = *(const float4*)&dinv[rbase + kg * 4];
    const float dvj[4] = {dv.x, dv.y, dv.z, dv.w};
#pragma unroll
    for (int cti = 0; cti < 2; ++cti) {
        const int ct = w * 2 + cti;
        const unsigned short* wrow = Wt + (size_t)(ct * 16 + lr) * HID + kg * 8;
        f32x4 acc = {0.f, 0.f, 0.f, 0.f};
#pragma unroll
        for (int s = 0; s < 4; ++s) {
            bf16x8 bf = *(const bf16x8*)(wrow + s * 32);
            acc = __builtin_amdgcn_mfma_f32_16x16x32_bf16(af[s], bf, acc, 0, 0, 0);
        }
#pragma unroll
        for (int j = 0; j < 4; ++j)
            Aout[(size_t)(rbase + kg * 4 + j) * HID + ct * 16 + lr] = f2bf(acc[j] * dvj[j]);
    }
}

__device__ __forceinline__ void pool_combine(const float4 (*po)[32], const int* bid,
        float* __restrict__ pooled, int tid)
{
    if (tid < 32) {
#pragma unroll
        for (int i = 0; i < 16; ++i) {
            bool lead = true;
            for (int j = 0; j < i; ++j) lead = lead && (bid[j] != bid[i]);
            if (lead) {
                float4 s = po[i][tid];
                for (int j = i + 1; j < 16; ++j)
                    if (bid[j] == bid[i]) add4(s, po[j][tid]);
                float* p = &pooled[bid[i] * FEAT + tid * 4];
                atomicAdd(p + 0, s.x);
                atomicAdd(p + 1, s.y);
                atomicAdd(p + 2, s.z);
                atomicAdd(p + 3, s.w);
            }
        }
    }
}

// ================= fused: x pool + x->bf16 + gemm W0 -> M =================
__global__ __launch_bounds__(256) void k_x_gemm(const float* __restrict__ x,
        const int* __restrict__ batch, const unsigned short* __restrict__ Wt,
        const float* __restrict__ dinv, float* __restrict__ pooled,
        unsigned short* __restrict__ M)
{
    __shared__ __align__(16) unsigned short sh[16 * 128];
    __shared__ float4 po[16][32];
    __shared__ int bid[16];
    const int t = threadIdx.x;
    const int w = t >> 6;
    const int lane = t & 63;
    const int grp = lane >> 4;
    const int l16 = lane & 15;
    const int nloc = w * 4 + grp;
    const int n = blockIdx.x * 16 + nloc;

    const float4* xr = (const float4*)(x + (size_t)n * HID + l16 * 8);
    float4 a = xr[0], b = xr[1];
    uint4 ob;
    ob.x = (unsigned)f2bf(a.x) | ((unsigned)f2bf(a.y) << 16);
    ob.y = (unsigned)f2bf(a.z) | ((unsigned)f2bf(a.w) << 16);
    ob.z = (unsigned)f2bf(b.x) | ((unsigned)f2bf(b.y) << 16);
    ob.w = (unsigned)f2bf(b.z) | ((unsigned)f2bf(b.w) << 16);
    *(uint4*)((char*)sh + swz(nloc, l16)) = ob;
    po[nloc][l16 * 2]     = a;
    po[nloc][l16 * 2 + 1] = b;
    if (l16 == 0) bid[nloc] = batch[n];
    __syncthreads();

    tile_gemm(sh, Wt, dinv, M, blockIdx.x * 16, w, lane);
    pool_combine(po, bid, pooled, t);
}

// ================= fused: aggregate + BN/ReLU + pool + gemm W_{L+1} -> Mout =================
__global__ __launch_bounds__(256) void k_aggemm(const unsigned short* __restrict__ Ain,
        const int* __restrict__ rowptr, const unsigned short* __restrict__ csr,
        const float* __restrict__ dinv, const float* __restrict__ bs,
        const float* __restrict__ gam, const float* __restrict__ bet,
        const float* __restrict__ rm, const float* __restrict__ rv,
        const int* __restrict__ batch, float* __restrict__ pooled,
        const unsigned short* __restrict__ Wt, unsigned short* __restrict__ Mout)
{
    __shared__ __align__(16) unsigned short sh[16 * 128];
    __shared__ float4 po[16][32];
    __shared__ int bid[16];
    const int t = threadIdx.x;
    const int w = t >> 6;
    const int lane = t & 63;
    const int grp = lane >> 4;
    const int l16 = lane & 15;
    const int nloc = w * 4 + grp;
    const int d = blockIdx.x * 16 + nloc;
    const uint4* __restrict__ A4 = (const uint4*)Ain;

    float acc[8];
    accinit(acc, A4[d * 16 + l16]);                 // self-loop term
    gather_rows(A4, csr, rowptr[d], rowptr[d + 1], l16, acc);

    float o[8];
    bn_relu(acc, dinv[d], l16 * 8, bs, gam, bet, rm, rv, o);

    uint4 ob;
    ob.x = (unsigned)f2bf(o[0]) | ((unsigned)f2bf(o[1]) << 16);
    ob.y = (unsigned)f2bf(o[2]) | ((unsigned)f2bf(o[3]) << 16);
    ob.z = (unsigned)f2bf(o[4]) | ((unsigned)f2bf(o[5]) << 16);
    ob.w = (unsigned)f2bf(o[6]) | ((unsigned)f2bf(o[7]) << 16);
    *(uint4*)((char*)sh + swz(nloc, l16)) = ob;
    po[nloc][l16 * 2]     = make_float4(o[0], o[1], o[2], o[3]);
    po[nloc][l16 * 2 + 1] = make_float4(o[4], o[5], o[6], o[7]);
    if (l16 == 0) bid[nloc] = batch[d];
    __syncthreads();

    tile_gemm(sh, Wt, dinv, Mout, blockIdx.x * 16, w, lane);
    pool_combine(po, bid, pooled, t);
}

// ================= last layer: aggregate + BN/ReLU + pool only =================
__global__ __launch_bounds__(256) void k_agg3(const unsigned short* __restrict__ Ain,
        const int* __restrict__ rowptr, const unsigned short* __restrict__ csr,
        const float* __restrict__ dinv, const float* __restrict__ bs,
        const float* __restrict__ gam, const float* __restrict__ bet,
        const float* __restrict__ rm, const float* __restrict__ rv,
        const int* __restrict__ batch, float* __restrict__ pooled)
{
    __shared__ float4 po[16][32];
    __shared__ int bid[16];
    const int t = threadIdx.x;
    const int w = t >> 6;
    const int lane = t & 63;
    const int grp = lane >> 4;
    const int l16 = lane & 15;
    const int nloc = w * 4 + grp;
    const int d = blockIdx.x * 16 + nloc;
    const uint4* __restrict__ A4 = (const uint4*)Ain;

    float acc[8];
    accinit(acc, A4[d * 16 + l16]);                 // self-loop term
    gather_rows(A4, csr, rowptr[d], rowptr[d + 1], l16, acc);

    float o[8];
    bn_relu(acc, dinv[d], l16 * 8, bs, gam, bet, rm, rv, o);

    po[nloc][l16 * 2]     = make_float4(o[0], o[1], o[2], o[3]);
    po[nloc][l16 * 2 + 1] = make_float4(o[4], o[5], o[6], o[7]);
    if (l16 == 0) bid[nloc] = batch[d];
    __syncthreads();
    pool_combine(po, bid, pooled, t);
}

// ---- classifier + log_softmax ----
__global__ void k_final(const float* __restrict__ pooled, const int* __restrict__ batch,
        const float* __restrict__ Wc, const float* __restrict__ bc, float* __restrict__ out)
{
    __shared__ float lg[NOUT];
    int g = blockIdx.x;
    int t = threadIdx.x;  // 64
    int start = lbound(batch, NN, g);
    int end = lbound(batch, NN, g + 1);
    float inv = 1.f / fmaxf((float)(end - start), 1.f);
    if (t < NOUT) {
        float acc = bc[t];
        for (int c = 0; c < FEAT; ++c)
            acc = fmaf(pooled[g * FEAT + c] * inv, Wc[c * NOUT + t], acc);
        lg[t] = acc;
    }
    __syncthreads();
    if (t == 0) {
        float m = -1e30f;
        for (int o = 0; o < NOUT; ++o) m = fmaxf(m, lg[o]);
        float ssum = 0.f;
        for (int o = 0; o < NOUT; ++o) ssum += expf(lg[o] - m);
        float lse = m + logf(ssum);
        for (int o = 0; o < NOUT; ++o) out[g * NOUT + o] = lg[o] - lse;
    }
}

extern "C" void kernel_launch(void* const* d_in, const int* in_sizes, int n_in,
                              void* d_out, int out_size, void* d_ws, size_t ws_size,
                              hipStream_t stream)
{
    const float* x      = (const float*)d_in[0];
    const int*   ei     = (const int*)d_in[1];
    const int*   batch  = (const int*)d_in[2];
    const float* Ws     = (const float*)d_in[3];
    const float* bs     = (const float*)d_in[4];
    const float* gammas = (const float*)d_in[5];
    const float* betas  = (const float*)d_in[6];
    const float* rms    = (const float*)d_in[7];
    const float* rvs    = (const float*)d_in[8];
    const float* Wc     = (const float*)d_in[9];
    const float* bc     = (const float*)d_in[10];
    float* out = (float*)d_out;

    float*          dinv     = (float*)d_ws;                   // NN
    float*          pooled   = dinv + NN;                      // NG*FEAT
    unsigned short* M        = (unsigned short*)(pooled + NG * FEAT);  // NN*HID bf16
    unsigned short* M2       = M + (size_t)NN * HID;           // NN*HID bf16
    unsigned short* Wt       = M2 + (size_t)NN * HID;          // 3*HID*HID bf16
    int*            rowptr   = (int*)(Wt + 3 * HID * HID);     // NN+1
    int*            bh       = rowptr + NN + 1;                // NBKT
    int*            bbase    = bh + NBKT;                      // NBKT+1
    unsigned int*   bucketed = (unsigned int*)(bbase + NBKT + 1); // NBKT*CAPB
    unsigned short* csr      = (unsigned short*)(bucketed + (size_t)NBKT * CAPB); // NE

    // prep: W transpose + zero bh + zero pooled (replaces both memsets)
    k_prep<<<27, 256, 0, stream>>>(Ws, Wt, bh, pooled);

    // bucketed CSR build (once; reused for all 3 layers)
    k_scatter<<<NSB, 256, 0, stream>>>(ei, bh, bucketed);
    k_hscan<<<1, NBKT, 0, stream>>>(bh, bbase);
    k_bucket_csr<<<NBB, 256, 0, stream>>>(bucketed, bh, bbase, csr, rowptr, dinv);

    // layer pipeline (B never materialized)
    k_x_gemm<<<NTILE, 256, 0, stream>>>(x, batch, Wt, dinv, pooled, M);
    k_aggemm<<<NTILE, 256, 0, stream>>>(M, rowptr, csr, dinv,
        bs, gammas, betas, rms, rvs, batch, pooled + 1 * HID,
        Wt + 1 * HID * HID, M2);
    k_aggemm<<<NTILE, 256, 0, stream>>>(M2, rowptr, csr, dinv,
        bs + HID, gammas + HID, betas + HID, rms + HID, rvs + HID,
        batch, pooled + 2 * HID, Wt + 2 * HID * HID, M);
    k_agg3<<<NTILE, 256, 0, stream>>>(M, rowptr, csr, dinv,
        bs + 2 * HID, gammas + 2 * HID, betas + 2 * HID, rms + 2 * HID, rvs + 2 * HID,
        batch, pooled + 3 * HID);

    k_final<<<NG, 64, 0, stream>>>(pooled, batch, Wc, bc, out);
}